// Round 1
// baseline (15741.032 us; speedup 1.0000x reference)
//
#include <hip/hip_runtime.h>

typedef _Float16 f16;
typedef _Float16 f16x8 __attribute__((ext_vector_type(8)));
typedef _Float16 f16x4 __attribute__((ext_vector_type(4)));
typedef float    f32x4 __attribute__((ext_vector_type(4)));

#define T_STEPS 256
#define B_ROWS  128
#define I_DIM   1024
#define H_DIM   1024
#define O_DIM   512
#define TBROWS  (T_STEPS * B_ROWS)   // 32768

// ---------------- init: zero h state + barrier ----------------
__global__ void k_init(f16* h16, float* h32, unsigned* bar) {
    int i = blockIdx.x * 256 + threadIdx.x;
    if (i < B_ROWS * H_DIM) { h16[i] = (f16)0.f; h32[i] = 0.f; }
    if (blockIdx.x == 0 && threadIdx.x < 16) bar[threadIdx.x] = 0u;
}

// ---------------- two-level device barrier (128 WGs) ----------------
__device__ __forceinline__ void gbar(unsigned* bar) {
    __syncthreads();
    if (threadIdx.x == 0) {
        __threadfence();  // release: flush L2 to coherence point
        unsigned gen = __hip_atomic_load(&bar[9], __ATOMIC_RELAXED, __HIP_MEMORY_SCOPE_AGENT);
        int grp = blockIdx.x & 7;
        unsigned a = __hip_atomic_fetch_add(&bar[grp], 1u, __ATOMIC_ACQ_REL, __HIP_MEMORY_SCOPE_AGENT);
        if (a == 15u) {  // last of my group of 16
            unsigned b8 = __hip_atomic_fetch_add(&bar[8], 1u, __ATOMIC_ACQ_REL, __HIP_MEMORY_SCOPE_AGENT);
            if (b8 == 7u) {  // last group overall: reset counters, bump generation
                #pragma unroll
                for (int i = 0; i < 9; ++i)
                    __hip_atomic_store(&bar[i], 0u, __ATOMIC_RELAXED, __HIP_MEMORY_SCOPE_AGENT);
                __hip_atomic_fetch_add(&bar[9], 1u, __ATOMIC_RELEASE, __HIP_MEMORY_SCOPE_AGENT);
            }
        }
        while (__hip_atomic_load(&bar[9], __ATOMIC_RELAXED, __HIP_MEMORY_SCOPE_AGENT) == gen)
            __builtin_amdgcn_s_sleep(1);
        __threadfence();  // acquire: invalidate L1/L2 so fresh data is seen
    }
    __syncthreads();
}

// ---------------- gate GEMM: G_g = (x + noise_g) @ Wx_g^T  (fp16 out) ----------------
// grid (TBROWS/128, H/128, 3), 256 threads; BM=BN=128, BK=32
__global__ __launch_bounds__(256) void k_gate_gemm(
    const float* __restrict__ x,
    const float* __restrict__ nR, const float* __restrict__ nZ, const float* __restrict__ nH,
    const float* __restrict__ WxR, const float* __restrict__ WxZ, const float* __restrict__ WxH,
    f16* __restrict__ GR, f16* __restrict__ GZ, f16* __restrict__ GH)
{
    const int g = blockIdx.z;
    const float* noise = (g == 0) ? nR : (g == 1) ? nZ : nH;
    const float* W     = (g == 0) ? WxR : (g == 1) ? WxZ : WxH;
    f16* G             = (g == 0) ? GR : (g == 1) ? GZ : GH;

    __shared__ f16 As[128 * 40];   // stride 40 halves (80B) -> 2-way banks only
    __shared__ f16 Bs[128 * 40];

    const int t = threadIdx.x;
    const int lane = t & 63;
    const int w  = t >> 6;
    const int wm = w & 1, wn = w >> 1;
    const int rowBase = blockIdx.x * 128;
    const int colBase = blockIdx.y * 128;

    const int srow = t >> 1;
    const int sk   = (t & 1) * 16;

    f32x4 acc[4][4] = {};

    for (int kt = 0; kt < I_DIM; kt += 32) {
        {   // stage A = x + noise, convert fp16
            const float* xp = x     + (size_t)(rowBase + srow) * I_DIM + kt + sk;
            const float* np = noise + (size_t)(rowBase + srow) * I_DIM + kt + sk;
            f16x8 t0, t1;
            #pragma unroll
            for (int q = 0; q < 2; ++q) {
                float4 a = ((const float4*)xp)[q];
                float4 b = ((const float4*)np)[q];
                t0[q*4+0] = (f16)(a.x + b.x); t0[q*4+1] = (f16)(a.y + b.y);
                t0[q*4+2] = (f16)(a.z + b.z); t0[q*4+3] = (f16)(a.w + b.w);
            }
            #pragma unroll
            for (int q = 0; q < 2; ++q) {
                float4 a = ((const float4*)xp)[q+2];
                float4 b = ((const float4*)np)[q+2];
                t1[q*4+0] = (f16)(a.x + b.x); t1[q*4+1] = (f16)(a.y + b.y);
                t1[q*4+2] = (f16)(a.z + b.z); t1[q*4+3] = (f16)(a.w + b.w);
            }
            *(f16x8*)&As[srow*40 + sk]     = t0;
            *(f16x8*)&As[srow*40 + sk + 8] = t1;
            // stage B = W rows (K-contiguous, NT layout)
            const float* wp = W + (size_t)(colBase + srow) * I_DIM + kt + sk;
            #pragma unroll
            for (int q = 0; q < 2; ++q) {
                float4 a = ((const float4*)wp)[q];
                t0[q*4+0] = (f16)a.x; t0[q*4+1] = (f16)a.y; t0[q*4+2] = (f16)a.z; t0[q*4+3] = (f16)a.w;
            }
            #pragma unroll
            for (int q = 0; q < 2; ++q) {
                float4 a = ((const float4*)wp)[q+2];
                t1[q*4+0] = (f16)a.x; t1[q*4+1] = (f16)a.y; t1[q*4+2] = (f16)a.z; t1[q*4+3] = (f16)a.w;
            }
            *(f16x8*)&Bs[srow*40 + sk]     = t0;
            *(f16x8*)&Bs[srow*40 + sk + 8] = t1;
        }
        __syncthreads();
        f16x8 af[4], bf[4];
        #pragma unroll
        for (int i = 0; i < 4; ++i)
            af[i] = *(const f16x8*)&As[(wm*64 + i*16 + (lane & 15))*40 + ((lane >> 4) * 8)];
        #pragma unroll
        for (int i = 0; i < 4; ++i)
            bf[i] = *(const f16x8*)&Bs[(wn*64 + i*16 + (lane & 15))*40 + ((lane >> 4) * 8)];
        #pragma unroll
        for (int i = 0; i < 4; ++i)
            #pragma unroll
            for (int j = 0; j < 4; ++j)
                acc[i][j] = __builtin_amdgcn_mfma_f32_16x16x32_f16(af[i], bf[j], acc[i][j], 0, 0, 0);
        __syncthreads();
    }
    // epilogue: C row = (lane>>4)*4 + r, col = lane&15 (m89-verified layout)
    #pragma unroll
    for (int i = 0; i < 4; ++i) {
        const int row = rowBase + wm*64 + i*16 + ((lane >> 4) * 4);
        #pragma unroll
        for (int j = 0; j < 4; ++j) {
            const int col = colBase + wn*64 + j*16 + (lane & 15);
            #pragma unroll
            for (int r = 0; r < 4; ++r)
                G[(size_t)(row + r) * H_DIM + col] = (f16)acc[i][j][r];
        }
    }
}

// ---------------- output GEMM: out = Hs @ Wout^T + bout (fp32 out) ----------------
// grid (TBROWS/128, O/128), 256 threads
__global__ __launch_bounds__(256) void k_out_gemm(
    const f16* __restrict__ Hs, const float* __restrict__ Wout,
    const float* __restrict__ bout, float* __restrict__ out)
{
    __shared__ f16 As[128 * 40];
    __shared__ f16 Bs[128 * 40];

    const int t = threadIdx.x;
    const int lane = t & 63;
    const int w  = t >> 6;
    const int wm = w & 1, wn = w >> 1;
    const int rowBase = blockIdx.x * 128;
    const int colBase = blockIdx.y * 128;

    const int srow = t >> 1;
    const int sk   = (t & 1) * 16;

    f32x4 acc[4][4] = {};

    for (int kt = 0; kt < H_DIM; kt += 32) {
        {
            const f16* ap = Hs + (size_t)(rowBase + srow) * H_DIM + kt + sk;
            *(f16x8*)&As[srow*40 + sk]     = *(const f16x8*)ap;
            *(f16x8*)&As[srow*40 + sk + 8] = *(const f16x8*)(ap + 8);
            const float* wp = Wout + (size_t)(colBase + srow) * H_DIM + kt + sk;
            f16x8 t0, t1;
            #pragma unroll
            for (int q = 0; q < 2; ++q) {
                float4 a = ((const float4*)wp)[q];
                t0[q*4+0] = (f16)a.x; t0[q*4+1] = (f16)a.y; t0[q*4+2] = (f16)a.z; t0[q*4+3] = (f16)a.w;
            }
            #pragma unroll
            for (int q = 0; q < 2; ++q) {
                float4 a = ((const float4*)wp)[q+2];
                t1[q*4+0] = (f16)a.x; t1[q*4+1] = (f16)a.y; t1[q*4+2] = (f16)a.z; t1[q*4+3] = (f16)a.w;
            }
            *(f16x8*)&Bs[srow*40 + sk]     = t0;
            *(f16x8*)&Bs[srow*40 + sk + 8] = t1;
        }
        __syncthreads();
        f16x8 af[4], bf[4];
        #pragma unroll
        for (int i = 0; i < 4; ++i)
            af[i] = *(const f16x8*)&As[(wm*64 + i*16 + (lane & 15))*40 + ((lane >> 4) * 8)];
        #pragma unroll
        for (int i = 0; i < 4; ++i)
            bf[i] = *(const f16x8*)&Bs[(wn*64 + i*16 + (lane & 15))*40 + ((lane >> 4) * 8)];
        #pragma unroll
        for (int i = 0; i < 4; ++i)
            #pragma unroll
            for (int j = 0; j < 4; ++j)
                acc[i][j] = __builtin_amdgcn_mfma_f32_16x16x32_f16(af[i], bf[j], acc[i][j], 0, 0, 0);
        __syncthreads();
    }
    #pragma unroll
    for (int i = 0; i < 4; ++i) {
        const int row = rowBase + wm*64 + i*16 + ((lane >> 4) * 4);
        #pragma unroll
        for (int j = 0; j < 4; ++j) {
            const int col = colBase + wn*64 + j*16 + (lane & 15);
            const float bb = bout[col];
            #pragma unroll
            for (int r = 0; r < 4; ++r)
                out[(size_t)(row + r) * O_DIM + col] = acc[i][j][r] + bb;
        }
    }
}

// ---------------- persistent recurrent kernel ----------------
// 128 WGs x 256 thr. WG g<64: owns R cols [g*16, g*16+16) + Hhat/update for same cols.
// WG g>=64: owns Z cols [(g-64)*16, ...).
// Weights for owned columns resident in LDS (fp16). Per step:
//   phase1: pre = G + h @ W^T (+bias); R->Rh write, Z write.  [barrier]
//   phase2 (R-owners): Hhat = tanh(Gh + Rh @ Whh^T); h_new = Z*h + (1-Z)*Hhat. [barrier]
__global__ __launch_bounds__(256, 1) void k_recurrent(
    const f16* __restrict__ GR, const f16* __restrict__ GZ, const f16* __restrict__ GH,
    const float* __restrict__ WhR, const float* __restrict__ WhZ, const float* __restrict__ WhH,
    const float* __restrict__ bR, const float* __restrict__ bZ, const float* __restrict__ bH,
    f16* __restrict__ h16, float* __restrict__ h32,
    f16* __restrict__ Rh16, float* __restrict__ Z32,
    f16* __restrict__ Hs, unsigned* bar)
{
    __shared__ f16 WA[16 * 1032];   // phase-1 weights (WhR or WhZ), stride 1032 halves
    __shared__ f16 WB[16 * 1032];   // WhH (R-owners only)

    const int g = blockIdx.x;
    const bool isR = (g < 64);
    const int col0 = (isR ? g : g - 64) * 16;
    const int t = threadIdx.x;
    const int lane = t & 63;
    const int w = t >> 6;

    {   // load weight slices to LDS (fp32 -> fp16), once
        const float* Wp = isR ? WhR : WhZ;
        for (int i = t; i < 16 * 1024 / 4; i += 256) {
            int jj = (i * 4) >> 10, kk = (i * 4) & 1023;
            float4 v = ((const float4*)(Wp + (size_t)(col0 + jj) * H_DIM))[kk >> 2];
            f16x4 tv; tv[0] = (f16)v.x; tv[1] = (f16)v.y; tv[2] = (f16)v.z; tv[3] = (f16)v.w;
            *(f16x4*)&WA[jj * 1032 + kk] = tv;
        }
        if (isR) {
            for (int i = t; i < 16 * 1024 / 4; i += 256) {
                int jj = (i * 4) >> 10, kk = (i * 4) & 1023;
                float4 v = ((const float4*)(WhH + (size_t)(col0 + jj) * H_DIM))[kk >> 2];
                f16x4 tv; tv[0] = (f16)v.x; tv[1] = (f16)v.y; tv[2] = (f16)v.z; tv[3] = (f16)v.w;
                *(f16x4*)&WB[jj * 1032 + kk] = tv;
            }
        }
    }
    __syncthreads();

    const int col   = col0 + (lane & 15);
    const float biasA = (isR ? bR : bZ)[col];
    const float biasB = isR ? bH[col] : 0.f;
    const int rbase = w * 32;              // wave handles row tiles rbase, rbase+16
    const int r0    = rbase + (lane & 15);
    const int kl    = (lane >> 4) * 8;

    for (int step = 0; step < T_STEPS; ++step) {
        // ---- phase 1 ----
        f32x4 c0 = {}, c1 = {};
        #pragma unroll 8
        for (int kk = 0; kk < 32; ++kk) {
            f16x8 a0 = *(const f16x8*)&h16[(size_t)r0 * H_DIM + kk*32 + kl];
            f16x8 a1 = *(const f16x8*)&h16[(size_t)(r0 + 16) * H_DIM + kk*32 + kl];
            f16x8 b  = *(const f16x8*)&WA[(lane & 15) * 1032 + kk*32 + kl];
            c0 = __builtin_amdgcn_mfma_f32_16x16x32_f16(a0, b, c0, 0, 0, 0);
            c1 = __builtin_amdgcn_mfma_f32_16x16x32_f16(a1, b, c1, 0, 0, 0);
        }
        const f16* Gg = isR ? GR : GZ;
        #pragma unroll
        for (int rt = 0; rt < 2; ++rt) {
            f32x4 c = rt ? c1 : c0;
            #pragma unroll
            for (int r = 0; r < 4; ++r) {
                int row = rbase + rt*16 + ((lane >> 4) * 4) + r;
                size_t idx = (size_t)row * H_DIM + col;
                float pre = c[r] + (float)Gg[(size_t)step * (B_ROWS * H_DIM) + idx] + biasA;
                float s = 1.f / (1.f + __expf(-pre));
                if (isR) Rh16[idx] = (f16)(s * h32[idx]);
                else     Z32[idx]  = s;
            }
        }
        gbar(bar);

        // ---- phase 2 (R owners) ----
        if (isR) {
            f32x4 d0 = {}, d1 = {};
            #pragma unroll 8
            for (int kk = 0; kk < 32; ++kk) {
                f16x8 a0 = *(const f16x8*)&Rh16[(size_t)r0 * H_DIM + kk*32 + kl];
                f16x8 a1 = *(const f16x8*)&Rh16[(size_t)(r0 + 16) * H_DIM + kk*32 + kl];
                f16x8 b  = *(const f16x8*)&WB[(lane & 15) * 1032 + kk*32 + kl];
                d0 = __builtin_amdgcn_mfma_f32_16x16x32_f16(a0, b, d0, 0, 0, 0);
                d1 = __builtin_amdgcn_mfma_f32_16x16x32_f16(a1, b, d1, 0, 0, 0);
            }
            #pragma unroll
            for (int rt = 0; rt < 2; ++rt) {
                f32x4 d = rt ? d1 : d0;
                #pragma unroll
                for (int r = 0; r < 4; ++r) {
                    int row = rbase + rt*16 + ((lane >> 4) * 4) + r;
                    size_t idx = (size_t)row * H_DIM + col;
                    float pre = d[r] + (float)GH[(size_t)step * (B_ROWS * H_DIM) + idx] + biasB;
                    float hh = tanhf(pre);
                    float z  = Z32[idx];
                    float ho = h32[idx];
                    float hn = z * ho + (1.f - z) * hh;
                    h32[idx] = hn;
                    f16 hf = (f16)hn;
                    h16[idx] = hf;
                    Hs[(size_t)step * (B_ROWS * H_DIM) + idx] = hf;
                }
            }
        }
        gbar(bar);
    }
}

extern "C" void kernel_launch(void* const* d_in, const int* in_sizes, int n_in,
                              void* d_out, int out_size, void* d_ws, size_t ws_size,
                              hipStream_t stream) {
    const float* x    = (const float*)d_in[0];
    const float* rn   = (const float*)d_in[1];
    const float* zn   = (const float*)d_in[2];
    const float* hn   = (const float*)d_in[3];
    const float* Wxz  = (const float*)d_in[4];
    const float* Wxr  = (const float*)d_in[5];
    const float* Wxh  = (const float*)d_in[6];
    const float* Whz  = (const float*)d_in[7];
    const float* bz   = (const float*)d_in[8];
    const float* Whr  = (const float*)d_in[9];
    const float* br   = (const float*)d_in[10];
    const float* Whh  = (const float*)d_in[11];
    const float* bh   = (const float*)d_in[12];
    const float* Wout = (const float*)d_in[13];
    const float* bout = (const float*)d_in[14];
    float* out = (float*)d_out;

    char* ws = (char*)d_ws;
    size_t off = 0;
    f16* GR   = (f16*)(ws + off); off += (size_t)TBROWS * H_DIM * 2;  // 64 MB
    f16* GZ   = (f16*)(ws + off); off += (size_t)TBROWS * H_DIM * 2;
    f16* GH   = (f16*)(ws + off); off += (size_t)TBROWS * H_DIM * 2;
    f16* Hs   = (f16*)(ws + off); off += (size_t)TBROWS * H_DIM * 2;
    f16* h16  = (f16*)(ws + off); off += (size_t)B_ROWS * H_DIM * 2;
    float* h32 = (float*)(ws + off); off += (size_t)B_ROWS * H_DIM * 4;
    f16* Rh16 = (f16*)(ws + off); off += (size_t)B_ROWS * H_DIM * 2;
    float* Z32 = (float*)(ws + off); off += (size_t)B_ROWS * H_DIM * 4;
    unsigned* bar = (unsigned*)(ws + off); off += 256;

    k_init<<<512, 256, 0, stream>>>(h16, h32, bar);
    k_gate_gemm<<<dim3(TBROWS / 128, H_DIM / 128, 3), 256, 0, stream>>>(
        x, rn, zn, hn, Wxr, Wxz, Wxh, GR, GZ, GH);
    k_recurrent<<<128, 256, 0, stream>>>(
        GR, GZ, GH, Whr, Whz, Whh, br, bz, bh, h16, h32, Rh16, Z32, Hs, bar);
    k_out_gemm<<<dim3(TBROWS / 128, O_DIM / 128), 256, 0, stream>>>(Hs, Wout, bout, out);
}

// Round 2
// 7794.411 us; speedup vs baseline: 2.0195x; 2.0195x over previous
//
#include <hip/hip_runtime.h>

typedef _Float16 f16;
typedef _Float16 f16x8 __attribute__((ext_vector_type(8)));
typedef _Float16 f16x4 __attribute__((ext_vector_type(4)));
typedef float    f32x4 __attribute__((ext_vector_type(4)));

#define T_STEPS 256
#define B_ROWS  128
#define I_DIM   1024
#define H_DIM   1024
#define O_DIM   512
#define TBROWS  (T_STEPS * B_ROWS)   // 32768
#define BH      (B_ROWS * H_DIM)     // 131072
#define NWG     64

// ---------------- init: zero barrier ----------------
__global__ void k_init(unsigned* bar) {
    if (threadIdx.x < 16) bar[threadIdx.x] = 0u;
}

// ---------- device-coherent (MALL) load/store: bypass L1+L2 ----------
template<int K>
__device__ __forceinline__ f16x8 gload_cc(const f16* p) {
    f16x8 r;
    asm volatile("global_load_dwordx4 %0, %1, off offset:%c2 sc0 sc1"
                 : "=v"(r) : "v"(p), "n"(K * 64));
    return r;
}
template<int K> struct Iss {
    static __device__ __forceinline__ void go(f16x8* fr, const f16* p) {
        fr[K] = gload_cc<K>(p);
        Iss<K + 1>::go(fr, p);
    }
};
template<> struct Iss<32> {
    static __device__ __forceinline__ void go(f16x8*, const f16*) {}
};
__device__ __forceinline__ void gstore8_cc(f16* p, f16x4 v) {
    asm volatile("global_store_dwordx2 %0, %1, off sc0 sc1"
                 :: "v"(p), "v"(v) : "memory");
}

// ---------- zero-bulk-op device barrier (64 WGs, relaxed atomics only) ----------
__device__ __forceinline__ void gbar(unsigned* bar) {
    // every wave: its sc1 write-through stores must be at the coherence point
    asm volatile("s_waitcnt vmcnt(0) lgkmcnt(0)" ::: "memory");
    __syncthreads();
    if (threadIdx.x == 0) {
        unsigned gen = __hip_atomic_load(&bar[1], __ATOMIC_RELAXED, __HIP_MEMORY_SCOPE_AGENT);
        unsigned a = __hip_atomic_fetch_add(&bar[0], 1u, __ATOMIC_RELAXED, __HIP_MEMORY_SCOPE_AGENT);
        if (a == NWG - 1) {
            __hip_atomic_store(&bar[0], 0u, __ATOMIC_RELAXED, __HIP_MEMORY_SCOPE_AGENT);
            __hip_atomic_fetch_add(&bar[1], 1u, __ATOMIC_RELAXED, __HIP_MEMORY_SCOPE_AGENT);
        } else {
            while (__hip_atomic_load(&bar[1], __ATOMIC_RELAXED, __HIP_MEMORY_SCOPE_AGENT) == gen)
                __builtin_amdgcn_s_sleep(2);
        }
    }
    __syncthreads();
    __builtin_amdgcn_sched_barrier(0);
}

// ---------------- gate GEMM: G_g = (x + noise_g) @ Wx_g^T  (fp16 out) ----------------
__global__ __launch_bounds__(256) void k_gate_gemm(
    const float* __restrict__ x,
    const float* __restrict__ nR, const float* __restrict__ nZ, const float* __restrict__ nH,
    const float* __restrict__ WxR, const float* __restrict__ WxZ, const float* __restrict__ WxH,
    f16* __restrict__ GR, f16* __restrict__ GZ, f16* __restrict__ GH)
{
    const int g = blockIdx.z;
    const float* noise = (g == 0) ? nR : (g == 1) ? nZ : nH;
    const float* W     = (g == 0) ? WxR : (g == 1) ? WxZ : WxH;
    f16* G             = (g == 0) ? GR : (g == 1) ? GZ : GH;

    __shared__ f16 As[128 * 40];
    __shared__ f16 Bs[128 * 40];

    const int t = threadIdx.x;
    const int lane = t & 63;
    const int w  = t >> 6;
    const int wm = w & 1, wn = w >> 1;
    const int rowBase = blockIdx.x * 128;
    const int colBase = blockIdx.y * 128;

    const int srow = t >> 1;
    const int sk   = (t & 1) * 16;

    f32x4 acc[4][4] = {};

    for (int kt = 0; kt < I_DIM; kt += 32) {
        {
            const float* xp = x     + (size_t)(rowBase + srow) * I_DIM + kt + sk;
            const float* np = noise + (size_t)(rowBase + srow) * I_DIM + kt + sk;
            f16x8 t0, t1;
            #pragma unroll
            for (int q = 0; q < 2; ++q) {
                float4 a = ((const float4*)xp)[q];
                float4 b = ((const float4*)np)[q];
                t0[q*4+0] = (f16)(a.x + b.x); t0[q*4+1] = (f16)(a.y + b.y);
                t0[q*4+2] = (f16)(a.z + b.z); t0[q*4+3] = (f16)(a.w + b.w);
            }
            #pragma unroll
            for (int q = 0; q < 2; ++q) {
                float4 a = ((const float4*)xp)[q+2];
                float4 b = ((const float4*)np)[q+2];
                t1[q*4+0] = (f16)(a.x + b.x); t1[q*4+1] = (f16)(a.y + b.y);
                t1[q*4+2] = (f16)(a.z + b.z); t1[q*4+3] = (f16)(a.w + b.w);
            }
            *(f16x8*)&As[srow*40 + sk]     = t0;
            *(f16x8*)&As[srow*40 + sk + 8] = t1;
            const float* wp = W + (size_t)(colBase + srow) * I_DIM + kt + sk;
            #pragma unroll
            for (int q = 0; q < 2; ++q) {
                float4 a = ((const float4*)wp)[q];
                t0[q*4+0] = (f16)a.x; t0[q*4+1] = (f16)a.y; t0[q*4+2] = (f16)a.z; t0[q*4+3] = (f16)a.w;
            }
            #pragma unroll
            for (int q = 0; q < 2; ++q) {
                float4 a = ((const float4*)wp)[q+2];
                t1[q*4+0] = (f16)a.x; t1[q*4+1] = (f16)a.y; t1[q*4+2] = (f16)a.z; t1[q*4+3] = (f16)a.w;
            }
            *(f16x8*)&Bs[srow*40 + sk]     = t0;
            *(f16x8*)&Bs[srow*40 + sk + 8] = t1;
        }
        __syncthreads();
        f16x8 af[4], bf[4];
        #pragma unroll
        for (int i = 0; i < 4; ++i)
            af[i] = *(const f16x8*)&As[(wm*64 + i*16 + (lane & 15))*40 + ((lane >> 4) * 8)];
        #pragma unroll
        for (int i = 0; i < 4; ++i)
            bf[i] = *(const f16x8*)&Bs[(wn*64 + i*16 + (lane & 15))*40 + ((lane >> 4) * 8)];
        #pragma unroll
        for (int i = 0; i < 4; ++i)
            #pragma unroll
            for (int j = 0; j < 4; ++j)
                acc[i][j] = __builtin_amdgcn_mfma_f32_16x16x32_f16(af[i], bf[j], acc[i][j], 0, 0, 0);
        __syncthreads();
    }
    #pragma unroll
    for (int i = 0; i < 4; ++i) {
        const int row = rowBase + wm*64 + i*16 + ((lane >> 4) * 4);
        #pragma unroll
        for (int j = 0; j < 4; ++j) {
            const int col = colBase + wn*64 + j*16 + (lane & 15);
            #pragma unroll
            for (int r = 0; r < 4; ++r)
                G[(size_t)(row + r) * H_DIM + col] = (f16)acc[i][j][r];
        }
    }
}

// ---------------- output GEMM: out = Hs @ Wout^T + bout (fp32 out) ----------------
__global__ __launch_bounds__(256) void k_out_gemm(
    const f16* __restrict__ Hs, const float* __restrict__ Wout,
    const float* __restrict__ bout, float* __restrict__ out)
{
    __shared__ f16 As[128 * 40];
    __shared__ f16 Bs[128 * 40];

    const int t = threadIdx.x;
    const int lane = t & 63;
    const int w  = t >> 6;
    const int wm = w & 1, wn = w >> 1;
    const int rowBase = blockIdx.x * 128;
    const int colBase = blockIdx.y * 128;

    const int srow = t >> 1;
    const int sk   = (t & 1) * 16;

    f32x4 acc[4][4] = {};

    for (int kt = 0; kt < H_DIM; kt += 32) {
        {
            const f16* ap = Hs + (size_t)(rowBase + srow) * H_DIM + kt + sk;
            *(f16x8*)&As[srow*40 + sk]     = *(const f16x8*)ap;
            *(f16x8*)&As[srow*40 + sk + 8] = *(const f16x8*)(ap + 8);
            const float* wp = Wout + (size_t)(colBase + srow) * H_DIM + kt + sk;
            f16x8 t0, t1;
            #pragma unroll
            for (int q = 0; q < 2; ++q) {
                float4 a = ((const float4*)wp)[q];
                t0[q*4+0] = (f16)a.x; t0[q*4+1] = (f16)a.y; t0[q*4+2] = (f16)a.z; t0[q*4+3] = (f16)a.w;
            }
            #pragma unroll
            for (int q = 0; q < 2; ++q) {
                float4 a = ((const float4*)wp)[q+2];
                t1[q*4+0] = (f16)a.x; t1[q*4+1] = (f16)a.y; t1[q*4+2] = (f16)a.z; t1[q*4+3] = (f16)a.w;
            }
            *(f16x8*)&Bs[srow*40 + sk]     = t0;
            *(f16x8*)&Bs[srow*40 + sk + 8] = t1;
        }
        __syncthreads();
        f16x8 af[4], bf[4];
        #pragma unroll
        for (int i = 0; i < 4; ++i)
            af[i] = *(const f16x8*)&As[(wm*64 + i*16 + (lane & 15))*40 + ((lane >> 4) * 8)];
        #pragma unroll
        for (int i = 0; i < 4; ++i)
            bf[i] = *(const f16x8*)&Bs[(wn*64 + i*16 + (lane & 15))*40 + ((lane >> 4) * 8)];
        #pragma unroll
        for (int i = 0; i < 4; ++i)
            #pragma unroll
            for (int j = 0; j < 4; ++j)
                acc[i][j] = __builtin_amdgcn_mfma_f32_16x16x32_f16(af[i], bf[j], acc[i][j], 0, 0, 0);
        __syncthreads();
    }
    #pragma unroll
    for (int i = 0; i < 4; ++i) {
        const int row = rowBase + wm*64 + i*16 + ((lane >> 4) * 4);
        #pragma unroll
        for (int j = 0; j < 4; ++j) {
            const int col = colBase + wn*64 + j*16 + (lane & 15);
            const float bb = bout[col];
            #pragma unroll
            for (int r = 0; r < 4; ++r)
                out[(size_t)(row + r) * O_DIM + col] = acc[i][j][r] + bb;
        }
    }
}

// ---------------- persistent recurrent kernel ----------------
// 64 WGs x 512 thr (8 waves). WG owns 16 hidden cols: computes R, Z, Hhat, h-update
// for those cols. Z and fp32 h-state live in REGISTERS (same wave, same rows each
// step). Cross-WG handoff: Rh and Hs[step] via device-coherent sc0sc1 ops only.
// Swapped MFMA: A = W-slice (LDS), B = h rows (global coherent). D-row = out-col,
// D-col = batch-row -> per-lane 4 consecutive out-cols, vectorized 8B epilogue I/O.
__global__ __launch_bounds__(512, 1) void k_recurrent(
    const f16* __restrict__ GR, const f16* __restrict__ GZ, const f16* __restrict__ GH,
    const float* __restrict__ WhR, const float* __restrict__ WhZ, const float* __restrict__ WhH,
    const float* __restrict__ bR, const float* __restrict__ bZ, const float* __restrict__ bH,
    f16* __restrict__ Rh, f16* __restrict__ Hs, unsigned* bar)
{
    __shared__ f16 WA[16 * 1032];   // WhR slice
    __shared__ f16 WB[16 * 1032];   // WhZ slice
    __shared__ f16 WC[16 * 1032];   // WhH slice

    const int t = threadIdx.x;
    const int lane = t & 63;
    const int w = t >> 6;
    const int col0 = blockIdx.x * 16;

    // stage weight slices fp32->fp16 into LDS
    for (int i = t; i < 4096; i += 512) {
        int jj = i >> 8;
        int kk = (i & 255) << 2;
        float4 v = *(const float4*)(WhR + (size_t)(col0 + jj) * H_DIM + kk);
        f16x4 tv; tv[0] = (f16)v.x; tv[1] = (f16)v.y; tv[2] = (f16)v.z; tv[3] = (f16)v.w;
        *(f16x4*)&WA[jj * 1032 + kk] = tv;
        v = *(const float4*)(WhZ + (size_t)(col0 + jj) * H_DIM + kk);
        tv[0] = (f16)v.x; tv[1] = (f16)v.y; tv[2] = (f16)v.z; tv[3] = (f16)v.w;
        *(f16x4*)&WB[jj * 1032 + kk] = tv;
        v = *(const float4*)(WhH + (size_t)(col0 + jj) * H_DIM + kk);
        tv[0] = (f16)v.x; tv[1] = (f16)v.y; tv[2] = (f16)v.z; tv[3] = (f16)v.w;
        *(f16x4*)&WC[jj * 1032 + kk] = tv;
    }
    __syncthreads();

    const int brow = w * 16 + (lane & 15);   // batch row this lane covers (B-col / D-col)
    const int arow = lane & 15;              // A-row index into weight LDS
    const int kcol = (lane >> 4) * 8;        // k sub-offset (halves)
    const int ocl  = (lane >> 4) * 4;        // out-col offset within the 16 (D-rows)

    const f32x4 bbr = *(const f32x4*)&bR[col0 + ocl];
    const f32x4 bbz = *(const f32x4*)&bZ[col0 + ocl];
    const f32x4 bbh = *(const f32x4*)&bH[col0 + ocl];

    const size_t eoff = (size_t)brow * H_DIM + col0 + ocl;  // epilogue element offset
    const size_t koff = (size_t)brow * H_DIM + kcol;        // k-loop base offset

#define CONS_RZ(B, VM)                                                           \
    asm volatile("s_waitcnt vmcnt(" #VM ")" ::: "memory");                       \
    __builtin_amdgcn_sched_barrier(0);                                           \
    _Pragma("unroll")                                                            \
    for (int i = 0; i < 8; ++i) {                                                \
        const int kk = (B) * 8 + i;                                              \
        f16x8 ar = *(const f16x8*)&WA[arow * 1032 + kk * 32 + kcol];             \
        f16x8 az = *(const f16x8*)&WB[arow * 1032 + kk * 32 + kcol];             \
        accR = __builtin_amdgcn_mfma_f32_16x16x32_f16(ar, fr[kk], accR, 0, 0, 0);\
        accZ = __builtin_amdgcn_mfma_f32_16x16x32_f16(az, fr[kk], accZ, 0, 0, 0);\
    }

#define CONS_H(B, VM)                                                            \
    asm volatile("s_waitcnt vmcnt(" #VM ")" ::: "memory");                       \
    __builtin_amdgcn_sched_barrier(0);                                           \
    _Pragma("unroll")                                                            \
    for (int i = 0; i < 8; ++i) {                                                \
        const int kk = (B) * 8 + i;                                              \
        f16x8 ah = *(const f16x8*)&WC[arow * 1032 + kk * 32 + kcol];             \
        accH = __builtin_amdgcn_mfma_f32_16x16x32_f16(ah, fr[kk], accH, 0, 0, 0);\
    }

    float h32r[4] = {0.f, 0.f, 0.f, 0.f};

    #pragma unroll 1
    for (int step = 0; step < T_STEPS; ++step) {
        const size_t sBH = (size_t)step * BH;
        // ---- phase 1: R and Z for own cols ----
        f32x4 accR = {}, accZ = {};
        f16x4 gr4 = *(const f16x4*)&GR[sBH + eoff];
        f16x4 gz4 = *(const f16x4*)&GZ[sBH + eoff];
        if (step > 0) {
            const f16* hb = Hs + (sBH - BH) + koff;
            f16x8 fr[32];
            Iss<0>::go(fr, hb);
            CONS_RZ(0, 24) CONS_RZ(1, 16) CONS_RZ(2, 8) CONS_RZ(3, 0)
        }
        float zr[4];
        f16x4 rhv;
        #pragma unroll
        for (int j = 0; j < 4; ++j) {
            float pr = accR[j] + (float)gr4[j] + bbr[j];
            float rr = 1.f / (1.f + __expf(-pr));
            rhv[j] = (f16)(rr * h32r[j]);
            float pz = accZ[j] + (float)gz4[j] + bbz[j];
            zr[j] = 1.f / (1.f + __expf(-pz));
        }
        gstore8_cc(Rh + eoff, rhv);
        gbar(bar);

        // ---- phase 2: Hhat + h update ----
        f32x4 accH = {};
        f16x4 gh4 = *(const f16x4*)&GH[sBH + eoff];
        {
            const f16* rb = Rh + koff;
            f16x8 fr[32];
            Iss<0>::go(fr, rb);
            CONS_H(0, 24) CONS_H(1, 16) CONS_H(2, 8) CONS_H(3, 0)
        }
        f16x4 hv;
        #pragma unroll
        for (int j = 0; j < 4; ++j) {
            float ph = accH[j] + (float)gh4[j] + bbh[j];
            float e = __expf(2.f * ph);
            float th = 1.f - 2.f / (e + 1.f);   // tanh, saturates gracefully
            float hn = zr[j] * h32r[j] + (1.f - zr[j]) * th;
            h32r[j] = hn;
            hv[j] = (f16)hn;
        }
        gstore8_cc(Hs + sBH + eoff, hv);
        gbar(bar);
    }
#undef CONS_RZ
#undef CONS_H
}

extern "C" void kernel_launch(void* const* d_in, const int* in_sizes, int n_in,
                              void* d_out, int out_size, void* d_ws, size_t ws_size,
                              hipStream_t stream) {
    const float* x    = (const float*)d_in[0];
    const float* rn   = (const float*)d_in[1];
    const float* zn   = (const float*)d_in[2];
    const float* hn   = (const float*)d_in[3];
    const float* Wxz  = (const float*)d_in[4];
    const float* Wxr  = (const float*)d_in[5];
    const float* Wxh  = (const float*)d_in[6];
    const float* Whz  = (const float*)d_in[7];
    const float* bz   = (const float*)d_in[8];
    const float* Whr  = (const float*)d_in[9];
    const float* br   = (const float*)d_in[10];
    const float* Whh  = (const float*)d_in[11];
    const float* bh   = (const float*)d_in[12];
    const float* Wout = (const float*)d_in[13];
    const float* bout = (const float*)d_in[14];
    float* out = (float*)d_out;

    char* ws = (char*)d_ws;
    size_t off = 0;
    f16* GR  = (f16*)(ws + off); off += (size_t)TBROWS * H_DIM * 2;  // 64 MB
    f16* GZ  = (f16*)(ws + off); off += (size_t)TBROWS * H_DIM * 2;
    f16* GH  = (f16*)(ws + off); off += (size_t)TBROWS * H_DIM * 2;
    f16* Hs  = (f16*)(ws + off); off += (size_t)TBROWS * H_DIM * 2;
    f16* Rh  = (f16*)(ws + off); off += (size_t)BH * 2;
    unsigned* bar = (unsigned*)(ws + off); off += 256;

    k_init<<<1, 64, 0, stream>>>(bar);
    k_gate_gemm<<<dim3(TBROWS / 128, H_DIM / 128, 3), 256, 0, stream>>>(
        x, rn, zn, hn, Wxr, Wxz, Wxh, GR, GZ, GH);
    k_recurrent<<<NWG, 512, 0, stream>>>(
        GR, GZ, GH, Whr, Whz, Whh, br, bz, bh, Rh, Hs, bar);
    k_out_gemm<<<dim3(TBROWS / 128, O_DIM / 128), 256, 0, stream>>>(Hs, Wout, bout, out);
}

// Round 4
// 7613.306 us; speedup vs baseline: 2.0676x; 1.0238x over previous
//
#include <hip/hip_runtime.h>

typedef _Float16 f16;
typedef _Float16 f16x8 __attribute__((ext_vector_type(8)));
typedef _Float16 f16x4 __attribute__((ext_vector_type(4)));
typedef float    f32x4 __attribute__((ext_vector_type(4)));

#define T_STEPS 256
#define B_ROWS  128
#define I_DIM   1024
#define H_DIM   1024
#define O_DIM   512
#define TBROWS  (T_STEPS * B_ROWS)   // 32768
#define BH      (B_ROWS * H_DIM)     // 131072
#define NWG     64

// ---------------- init: zero barrier ----------------
__global__ void k_init(unsigned* bar) {
    if (threadIdx.x < 16) bar[threadIdx.x] = 0u;
}

// ---------- cached load (L1+L2). Safe: every handoff address is
// first-touched AFTER its producer's MALL write (step-indexed buffers,
// dispatch-start acquire invalidated all L2s). ----------
template<int K>
__device__ __forceinline__ f16x8 gload(const f16* p) {
    f16x8 r;
    asm volatile("global_load_dwordx4 %0, %1, off offset:%c2"
                 : "=v"(r) : "v"(p), "n"(K * 64));
    return r;
}
template<int K> struct Iss {
    static __device__ __forceinline__ void go(f16x8* fr, const f16* p) {
        fr[K] = gload<K>(p);
        Iss<K + 1>::go(fr, p);
    }
};
template<> struct Iss<32> {
    static __device__ __forceinline__ void go(f16x8*, const f16*) {}
};
// write-through to MALL (cross-XCD visible without any fence)
__device__ __forceinline__ void gstore8_cc(f16* p, f16x4 v) {
    asm volatile("global_store_dwordx2 %0, %1, off sc0 sc1"
                 :: "v"(p), "v"(v) : "memory");
}

// ---------- zero-bulk-op device barrier (64 WGs, relaxed atomics only) ----------
__device__ __forceinline__ void gbar(unsigned* bar) {
    asm volatile("s_waitcnt vmcnt(0) lgkmcnt(0)" ::: "memory");
    __syncthreads();
    if (threadIdx.x == 0) {
        unsigned gen = __hip_atomic_load(&bar[1], __ATOMIC_RELAXED, __HIP_MEMORY_SCOPE_AGENT);
        unsigned a = __hip_atomic_fetch_add(&bar[0], 1u, __ATOMIC_RELAXED, __HIP_MEMORY_SCOPE_AGENT);
        if (a == NWG - 1) {
            __hip_atomic_store(&bar[0], 0u, __ATOMIC_RELAXED, __HIP_MEMORY_SCOPE_AGENT);
            __hip_atomic_fetch_add(&bar[1], 1u, __ATOMIC_RELAXED, __HIP_MEMORY_SCOPE_AGENT);
        } else {
            while (__hip_atomic_load(&bar[1], __ATOMIC_RELAXED, __HIP_MEMORY_SCOPE_AGENT) == gen)
                __builtin_amdgcn_s_sleep(1);
        }
    }
    __syncthreads();
    __builtin_amdgcn_sched_barrier(0);
}

// ---------------- gate GEMM: G_g = (x + noise_g) @ Wx_g^T  (fp16 out) ----------------
__global__ __launch_bounds__(256) void k_gate_gemm(
    const float* __restrict__ x,
    const float* __restrict__ nR, const float* __restrict__ nZ, const float* __restrict__ nH,
    const float* __restrict__ WxR, const float* __restrict__ WxZ, const float* __restrict__ WxH,
    f16* __restrict__ GR, f16* __restrict__ GZ, f16* __restrict__ GH)
{
    const int g = blockIdx.z;
    const float* noise = (g == 0) ? nR : (g == 1) ? nZ : nH;
    const float* W     = (g == 0) ? WxR : (g == 1) ? WxZ : WxH;
    f16* G             = (g == 0) ? GR : (g == 1) ? GZ : GH;

    __shared__ f16 As[128 * 40];
    __shared__ f16 Bs[128 * 40];

    const int t = threadIdx.x;
    const int lane = t & 63;
    const int w  = t >> 6;
    const int wm = w & 1, wn = w >> 1;
    const int rowBase = blockIdx.x * 128;
    const int colBase = blockIdx.y * 128;

    const int srow = t >> 1;
    const int sk   = (t & 1) * 16;

    f32x4 acc[4][4] = {};

    for (int kt = 0; kt < I_DIM; kt += 32) {
        {
            const float* xp = x     + (size_t)(rowBase + srow) * I_DIM + kt + sk;
            const float* np = noise + (size_t)(rowBase + srow) * I_DIM + kt + sk;
            f16x8 t0, t1;
            #pragma unroll
            for (int q = 0; q < 2; ++q) {
                float4 a = ((const float4*)xp)[q];
                float4 b = ((const float4*)np)[q];
                t0[q*4+0] = (f16)(a.x + b.x); t0[q*4+1] = (f16)(a.y + b.y);
                t0[q*4+2] = (f16)(a.z + b.z); t0[q*4+3] = (f16)(a.w + b.w);
            }
            #pragma unroll
            for (int q = 0; q < 2; ++q) {
                float4 a = ((const float4*)xp)[q+2];
                float4 b = ((const float4*)np)[q+2];
                t1[q*4+0] = (f16)(a.x + b.x); t1[q*4+1] = (f16)(a.y + b.y);
                t1[q*4+2] = (f16)(a.z + b.z); t1[q*4+3] = (f16)(a.w + b.w);
            }
            *(f16x8*)&As[srow*40 + sk]     = t0;
            *(f16x8*)&As[srow*40 + sk + 8] = t1;
            const float* wp = W + (size_t)(colBase + srow) * I_DIM + kt + sk;
            #pragma unroll
            for (int q = 0; q < 2; ++q) {
                float4 a = ((const float4*)wp)[q];
                t0[q*4+0] = (f16)a.x; t0[q*4+1] = (f16)a.y; t0[q*4+2] = (f16)a.z; t0[q*4+3] = (f16)a.w;
            }
            #pragma unroll
            for (int q = 0; q < 2; ++q) {
                float4 a = ((const float4*)wp)[q+2];
                t1[q*4+0] = (f16)a.x; t1[q*4+1] = (f16)a.y; t1[q*4+2] = (f16)a.z; t1[q*4+3] = (f16)a.w;
            }
            *(f16x8*)&Bs[srow*40 + sk]     = t0;
            *(f16x8*)&Bs[srow*40 + sk + 8] = t1;
        }
        __syncthreads();
        f16x8 af[4], bf[4];
        #pragma unroll
        for (int i = 0; i < 4; ++i)
            af[i] = *(const f16x8*)&As[(wm*64 + i*16 + (lane & 15))*40 + ((lane >> 4) * 8)];
        #pragma unroll
        for (int i = 0; i < 4; ++i)
            bf[i] = *(const f16x8*)&Bs[(wn*64 + i*16 + (lane & 15))*40 + ((lane >> 4) * 8)];
        #pragma unroll
        for (int i = 0; i < 4; ++i)
            #pragma unroll
            for (int j = 0; j < 4; ++j)
                acc[i][j] = __builtin_amdgcn_mfma_f32_16x16x32_f16(af[i], bf[j], acc[i][j], 0, 0, 0);
        __syncthreads();
    }
    #pragma unroll
    for (int i = 0; i < 4; ++i) {
        const int row = rowBase + wm*64 + i*16 + ((lane >> 4) * 4);
        #pragma unroll
        for (int j = 0; j < 4; ++j) {
            const int col = colBase + wn*64 + j*16 + (lane & 15);
            #pragma unroll
            for (int r = 0; r < 4; ++r)
                G[(size_t)(row + r) * H_DIM + col] = (f16)acc[i][j][r];
        }
    }
}

// ---------------- output GEMM: out = Hs @ Wout^T + bout (fp32 out) ----------------
__global__ __launch_bounds__(256) void k_out_gemm(
    const f16* __restrict__ Hs, const float* __restrict__ Wout,
    const float* __restrict__ bout, float* __restrict__ out)
{
    __shared__ f16 As[128 * 40];
    __shared__ f16 Bs[128 * 40];

    const int t = threadIdx.x;
    const int lane = t & 63;
    const int w  = t >> 6;
    const int wm = w & 1, wn = w >> 1;
    const int rowBase = blockIdx.x * 128;
    const int colBase = blockIdx.y * 128;

    const int srow = t >> 1;
    const int sk   = (t & 1) * 16;

    f32x4 acc[4][4] = {};

    for (int kt = 0; kt < H_DIM; kt += 32) {
        {
            const f16* ap = Hs + (size_t)(rowBase + srow) * H_DIM + kt + sk;
            *(f16x8*)&As[srow*40 + sk]     = *(const f16x8*)ap;
            *(f16x8*)&As[srow*40 + sk + 8] = *(const f16x8*)(ap + 8);
            const float* wp = Wout + (size_t)(colBase + srow) * H_DIM + kt + sk;
            f16x8 t0, t1;
            #pragma unroll
            for (int q = 0; q < 2; ++q) {
                float4 a = ((const float4*)wp)[q];
                t0[q*4+0] = (f16)a.x; t0[q*4+1] = (f16)a.y; t0[q*4+2] = (f16)a.z; t0[q*4+3] = (f16)a.w;
            }
            #pragma unroll
            for (int q = 0; q < 2; ++q) {
                float4 a = ((const float4*)wp)[q+2];
                t1[q*4+0] = (f16)a.x; t1[q*4+1] = (f16)a.y; t1[q*4+2] = (f16)a.z; t1[q*4+3] = (f16)a.w;
            }
            *(f16x8*)&Bs[srow*40 + sk]     = t0;
            *(f16x8*)&Bs[srow*40 + sk + 8] = t1;
        }
        __syncthreads();
        f16x8 af[4], bf[4];
        #pragma unroll
        for (int i = 0; i < 4; ++i)
            af[i] = *(const f16x8*)&As[(wm*64 + i*16 + (lane & 15))*40 + ((lane >> 4) * 8)];
        #pragma unroll
        for (int i = 0; i < 4; ++i)
            bf[i] = *(const f16x8*)&Bs[(wn*64 + i*16 + (lane & 15))*40 + ((lane >> 4) * 8)];
        #pragma unroll
        for (int i = 0; i < 4; ++i)
            #pragma unroll
            for (int j = 0; j < 4; ++j)
                acc[i][j] = __builtin_amdgcn_mfma_f32_16x16x32_f16(af[i], bf[j], acc[i][j], 0, 0, 0);
        __syncthreads();
    }
    #pragma unroll
    for (int i = 0; i < 4; ++i) {
        const int row = rowBase + wm*64 + i*16 + ((lane >> 4) * 4);
        #pragma unroll
        for (int j = 0; j < 4; ++j) {
            const int col = colBase + wn*64 + j*16 + (lane & 15);
            const float bb = bout[col];
            #pragma unroll
            for (int r = 0; r < 4; ++r)
                out[(size_t)(row + r) * O_DIM + col] = acc[i][j][r] + bb;
        }
    }
}

// ---------------- persistent recurrent kernel ----------------
// 64 WGs x 512 thr (8 waves). WG owns 16 hidden cols. Z and fp32 h-state live
// in registers. Handoff: Rh_all[step] / Hs[step] written sc0sc1 (MALL), read
// with PLAIN CACHED loads — step-indexed addresses are first-touched after the
// producer's MALL write, so per-XCD L2 absorbs the 64-WG broadcast (16 MB ->
// 2 MB per phase at MALL).
__global__ __launch_bounds__(512, 1) void k_recurrent(
    const f16* __restrict__ GR, const f16* __restrict__ GZ, const f16* __restrict__ GH,
    const float* __restrict__ WhR, const float* __restrict__ WhZ, const float* __restrict__ WhH,
    const float* __restrict__ bR, const float* __restrict__ bZ, const float* __restrict__ bH,
    f16* __restrict__ Rh_all, f16* __restrict__ Hs, unsigned* bar)
{
    __shared__ f16 WA[16 * 1032];   // WhR slice
    __shared__ f16 WB[16 * 1032];   // WhZ slice
    __shared__ f16 WC[16 * 1032];   // WhH slice

    const int t = threadIdx.x;
    const int lane = t & 63;
    const int w = t >> 6;
    const int col0 = blockIdx.x * 16;

    for (int i = t; i < 4096; i += 512) {
        int jj = i >> 8;
        int kk = (i & 255) << 2;
        float4 v = *(const float4*)(WhR + (size_t)(col0 + jj) * H_DIM + kk);
        f16x4 tv; tv[0] = (f16)v.x; tv[1] = (f16)v.y; tv[2] = (f16)v.z; tv[3] = (f16)v.w;
        *(f16x4*)&WA[jj * 1032 + kk] = tv;
        v = *(const float4*)(WhZ + (size_t)(col0 + jj) * H_DIM + kk);
        tv[0] = (f16)v.x; tv[1] = (f16)v.y; tv[2] = (f16)v.z; tv[3] = (f16)v.w;
        *(f16x4*)&WB[jj * 1032 + kk] = tv;
        v = *(const float4*)(WhH + (size_t)(col0 + jj) * H_DIM + kk);
        tv[0] = (f16)v.x; tv[1] = (f16)v.y; tv[2] = (f16)v.z; tv[3] = (f16)v.w;
        *(f16x4*)&WC[jj * 1032 + kk] = tv;
    }
    __syncthreads();

    const int brow = w * 16 + (lane & 15);   // batch row (B-col / D-col)
    const int arow = lane & 15;              // A-row into weight LDS
    const int kcol = (lane >> 4) * 8;        // k sub-offset (halves)
    const int ocl  = (lane >> 4) * 4;        // out-col offset (D-rows)

    const f32x4 bbr = *(const f32x4*)&bR[col0 + ocl];
    const f32x4 bbz = *(const f32x4*)&bZ[col0 + ocl];
    const f32x4 bbh = *(const f32x4*)&bH[col0 + ocl];

    const size_t eoff = (size_t)brow * H_DIM + col0 + ocl;
    const size_t koff = (size_t)brow * H_DIM + kcol;

#define CONS_RZ(B, VM)                                                           \
    asm volatile("s_waitcnt vmcnt(" #VM ")" ::: "memory");                       \
    __builtin_amdgcn_sched_barrier(0);                                           \
    _Pragma("unroll")                                                            \
    for (int i = 0; i < 8; ++i) {                                                \
        const int kk = (B) * 8 + i;                                              \
        f16x8 ar = *(const f16x8*)&WA[arow * 1032 + kk * 32 + kcol];             \
        f16x8 az = *(const f16x8*)&WB[arow * 1032 + kk * 32 + kcol];             \
        accR = __builtin_amdgcn_mfma_f32_16x16x32_f16(ar, fr[kk], accR, 0, 0, 0);\
        accZ = __builtin_amdgcn_mfma_f32_16x16x32_f16(az, fr[kk], accZ, 0, 0, 0);\
    }

#define CONS_H(B, VM)                                                            \
    asm volatile("s_waitcnt vmcnt(" #VM ")" ::: "memory");                       \
    __builtin_amdgcn_sched_barrier(0);                                           \
    _Pragma("unroll")                                                            \
    for (int i = 0; i < 8; ++i) {                                                \
        const int kk = (B) * 8 + i;                                              \
        f16x8 ah = *(const f16x8*)&WC[arow * 1032 + kk * 32 + kcol];             \
        accH = __builtin_amdgcn_mfma_f32_16x16x32_f16(ah, fr[kk], accH, 0, 0, 0);\
    }

    float h32r[4] = {0.f, 0.f, 0.f, 0.f};

    #pragma unroll 1
    for (int step = 0; step < T_STEPS; ++step) {
        const size_t sBH = (size_t)step * BH;
        // ---- phase 1: R and Z ----
        f32x4 accR = {}, accZ = {};
        f16x4 gr4 = *(const f16x4*)&GR[sBH + eoff];
        f16x4 gz4 = *(const f16x4*)&GZ[sBH + eoff];
        if (step > 0) {
            const f16* hb = Hs + (sBH - BH) + koff;
            f16x8 fr[32];
            Iss<0>::go(fr, hb);
            CONS_RZ(0, 24) CONS_RZ(1, 16) CONS_RZ(2, 8) CONS_RZ(3, 0)
        }
        float zr[4];
        f16x4 rhv;
        #pragma unroll
        for (int j = 0; j < 4; ++j) {
            float pr = accR[j] + (float)gr4[j] + bbr[j];
            float rr = 1.f / (1.f + __expf(-pr));
            rhv[j] = (f16)(rr * h32r[j]);
            float pz = accZ[j] + (float)gz4[j] + bbz[j];
            zr[j] = 1.f / (1.f + __expf(-pz));
        }
        gstore8_cc(Rh_all + sBH + eoff, rhv);
        gbar(bar);

        // ---- phase 2: Hhat + h update ----
        f32x4 accH = {};
        f16x4 gh4 = *(const f16x4*)&GH[sBH + eoff];
        {
            const f16* rb = Rh_all + sBH + koff;
            f16x8 fr[32];
            Iss<0>::go(fr, rb);
            CONS_H(0, 24) CONS_H(1, 16) CONS_H(2, 8) CONS_H(3, 0)
        }
        f16x4 hv;
        #pragma unroll
        for (int j = 0; j < 4; ++j) {
            float ph = accH[j] + (float)gh4[j] + bbh[j];
            float e = __expf(2.f * ph);
            float th = 1.f - 2.f / (e + 1.f);
            float hn = zr[j] * h32r[j] + (1.f - zr[j]) * th;
            h32r[j] = hn;
            hv[j] = (f16)hn;
        }
        gstore8_cc(Hs + sBH + eoff, hv);
        if (step < T_STEPS - 1) gbar(bar);
    }
#undef CONS_RZ
#undef CONS_H
}

extern "C" void kernel_launch(void* const* d_in, const int* in_sizes, int n_in,
                              void* d_out, int out_size, void* d_ws, size_t ws_size,
                              hipStream_t stream) {
    const float* x    = (const float*)d_in[0];
    const float* rn   = (const float*)d_in[1];
    const float* zn   = (const float*)d_in[2];
    const float* hn   = (const float*)d_in[3];
    const float* Wxz  = (const float*)d_in[4];
    const float* Wxr  = (const float*)d_in[5];
    const float* Wxh  = (const float*)d_in[6];
    const float* Whz  = (const float*)d_in[7];
    const float* bz   = (const float*)d_in[8];
    const float* Whr  = (const float*)d_in[9];
    const float* br   = (const float*)d_in[10];
    const float* Whh  = (const float*)d_in[11];
    const float* bh   = (const float*)d_in[12];
    const float* Wout = (const float*)d_in[13];
    const float* bout = (const float*)d_in[14];
    float* out = (float*)d_out;

    char* ws = (char*)d_ws;
    size_t off = 0;
    f16* GR     = (f16*)(ws + off); off += (size_t)TBROWS * H_DIM * 2;  // 64 MB
    f16* GZ     = (f16*)(ws + off); off += (size_t)TBROWS * H_DIM * 2;
    f16* GH     = (f16*)(ws + off); off += (size_t)TBROWS * H_DIM * 2;
    f16* Hs     = (f16*)(ws + off); off += (size_t)TBROWS * H_DIM * 2;
    f16* Rh_all = (f16*)(ws + off); off += (size_t)TBROWS * H_DIM * 2;
    unsigned* bar = (unsigned*)(ws + off); off += 256;

    k_init<<<1, 64, 0, stream>>>(bar);
    k_gate_gemm<<<dim3(TBROWS / 128, H_DIM / 128, 3), 256, 0, stream>>>(
        x, rn, zn, hn, Wxr, Wxz, Wxh, GR, GZ, GH);
    k_recurrent<<<NWG, 512, 0, stream>>>(
        GR, GZ, GH, Whr, Whz, Whh, br, bz, bh, Rh_all, Hs, bar);
    k_out_gemm<<<dim3(TBROWS / 128, O_DIM / 128), 256, 0, stream>>>(Hs, Wout, bout, out);
}

// Round 6
// 5999.188 us; speedup vs baseline: 2.6239x; 1.2691x over previous
//
#include <hip/hip_runtime.h>

typedef _Float16 f16;
typedef _Float16 f16x8 __attribute__((ext_vector_type(8)));
typedef _Float16 f16x4 __attribute__((ext_vector_type(4)));
typedef float    f32x4 __attribute__((ext_vector_type(4)));

#define T_STEPS 256
#define B_ROWS  128
#define I_DIM   1024
#define H_DIM   1024
#define O_DIM   512
#define TBROWS  (T_STEPS * B_ROWS)   // 32768
#define BH      (B_ROWS * H_DIM)     // 131072
#define NWG     64

// ---------------- init: zero flag array ----------------
__global__ void k_init(unsigned* flg) {
    for (int i = threadIdx.x; i < NWG * 16; i += 256) flg[i] = 0u;
}

// ---------- cached load (L1+L2). Safe: every handoff address is
// first-touched AFTER its producer's MALL write (step-indexed buffers,
// dispatch-start acquire invalidated all L2s; prior-replay stale lines
// hold the same deterministic values). ----------
template<int K>
__device__ __forceinline__ f16x8 gload(const f16* p) {
    f16x8 r;
    asm volatile("global_load_dwordx4 %0, %1, off offset:%c2"
                 : "=v"(r) : "v"(p), "n"(K * 64));
    return r;
}
template<int K> struct Iss {
    static __device__ __forceinline__ void go(f16x8* fr, const f16* p) {
        fr[K] = gload<K>(p);
        Iss<K + 1>::go(fr, p);
    }
};
template<> struct Iss<32> {
    static __device__ __forceinline__ void go(f16x8*, const f16*) {}
};
// write-through to MALL (cross-XCD visible without any fence)
__device__ __forceinline__ void gstore8_cc(f16* p, f16x4 v) {
    asm volatile("global_store_dwordx2 %0, %1, off sc0 sc1"
                 :: "v"(p), "v"(v) : "memory");
}

// ---------- atomic-free-contention flag-array device barrier ----------
// WG i publishes `gen` to its own 64B-padded line with a compiler-emitted
// agent-scope atomic store (no shared-line RMW -> no serialization; the
// R2/R4 counting barrier's 13us was 64 serialized RMWs on one line).
// Wave 0 polls all 64 flags (one per lane) with agent-scope atomic loads.
// Flags are monotone per WG -> deadlock-free; all 64 WGs co-resident.
__device__ __forceinline__ void fbar(unsigned* flg, int wg, unsigned gen, int w, int lane) {
    asm volatile("s_waitcnt vmcnt(0) lgkmcnt(0)" ::: "memory");   // data stores acked at MALL
    __syncthreads();
    if (threadIdx.x == 0)
        __hip_atomic_store(&flg[wg * 16], gen, __ATOMIC_RELAXED, __HIP_MEMORY_SCOPE_AGENT);
    if (w == 0) {
        while (__hip_atomic_load(&flg[lane * 16], __ATOMIC_RELAXED, __HIP_MEMORY_SCOPE_AGENT) < gen)
            __builtin_amdgcn_s_sleep(1);
    }
    __syncthreads();
    __builtin_amdgcn_sched_barrier(0);
}

// ---------------- gate GEMM: G_g = (x + noise_g) @ Wx_g^T  (fp16 out) ----------------
__global__ __launch_bounds__(256) void k_gate_gemm(
    const float* __restrict__ x,
    const float* __restrict__ nR, const float* __restrict__ nZ, const float* __restrict__ nH,
    const float* __restrict__ WxR, const float* __restrict__ WxZ, const float* __restrict__ WxH,
    f16* __restrict__ GR, f16* __restrict__ GZ, f16* __restrict__ GH)
{
    const int g = blockIdx.z;
    const float* noise = (g == 0) ? nR : (g == 1) ? nZ : nH;
    const float* W     = (g == 0) ? WxR : (g == 1) ? WxZ : WxH;
    f16* G             = (g == 0) ? GR : (g == 1) ? GZ : GH;

    __shared__ f16 As[128 * 40];
    __shared__ f16 Bs[128 * 40];

    const int t = threadIdx.x;
    const int lane = t & 63;
    const int w  = t >> 6;
    const int wm = w & 1, wn = w >> 1;
    const int rowBase = blockIdx.x * 128;
    const int colBase = blockIdx.y * 128;

    const int srow = t >> 1;
    const int sk   = (t & 1) * 16;

    f32x4 acc[4][4] = {};

    for (int kt = 0; kt < I_DIM; kt += 32) {
        {
            const float* xp = x     + (size_t)(rowBase + srow) * I_DIM + kt + sk;
            const float* np = noise + (size_t)(rowBase + srow) * I_DIM + kt + sk;
            f16x8 t0, t1;
            #pragma unroll
            for (int q = 0; q < 2; ++q) {
                float4 a = ((const float4*)xp)[q];
                float4 b = ((const float4*)np)[q];
                t0[q*4+0] = (f16)(a.x + b.x); t0[q*4+1] = (f16)(a.y + b.y);
                t0[q*4+2] = (f16)(a.z + b.z); t0[q*4+3] = (f16)(a.w + b.w);
            }
            #pragma unroll
            for (int q = 0; q < 2; ++q) {
                float4 a = ((const float4*)xp)[q+2];
                float4 b = ((const float4*)np)[q+2];
                t1[q*4+0] = (f16)(a.x + b.x); t1[q*4+1] = (f16)(a.y + b.y);
                t1[q*4+2] = (f16)(a.z + b.z); t1[q*4+3] = (f16)(a.w + b.w);
            }
            *(f16x8*)&As[srow*40 + sk]     = t0;
            *(f16x8*)&As[srow*40 + sk + 8] = t1;
            const float* wp = W + (size_t)(colBase + srow) * I_DIM + kt + sk;
            #pragma unroll
            for (int q = 0; q < 2; ++q) {
                float4 a = ((const float4*)wp)[q];
                t0[q*4+0] = (f16)a.x; t0[q*4+1] = (f16)a.y; t0[q*4+2] = (f16)a.z; t0[q*4+3] = (f16)a.w;
            }
            #pragma unroll
            for (int q = 0; q < 2; ++q) {
                float4 a = ((const float4*)wp)[q+2];
                t1[q*4+0] = (f16)a.x; t1[q*4+1] = (f16)a.y; t1[q*4+2] = (f16)a.z; t1[q*4+3] = (f16)a.w;
            }
            *(f16x8*)&Bs[srow*40 + sk]     = t0;
            *(f16x8*)&Bs[srow*40 + sk + 8] = t1;
        }
        __syncthreads();
        f16x8 af[4], bf[4];
        #pragma unroll
        for (int i = 0; i < 4; ++i)
            af[i] = *(const f16x8*)&As[(wm*64 + i*16 + (lane & 15))*40 + ((lane >> 4) * 8)];
        #pragma unroll
        for (int i = 0; i < 4; ++i)
            bf[i] = *(const f16x8*)&Bs[(wn*64 + i*16 + (lane & 15))*40 + ((lane >> 4) * 8)];
        #pragma unroll
        for (int i = 0; i < 4; ++i)
            #pragma unroll
            for (int j = 0; j < 4; ++j)
                acc[i][j] = __builtin_amdgcn_mfma_f32_16x16x32_f16(af[i], bf[j], acc[i][j], 0, 0, 0);
        __syncthreads();
    }
    #pragma unroll
    for (int i = 0; i < 4; ++i) {
        const int row = rowBase + wm*64 + i*16 + ((lane >> 4) * 4);
        #pragma unroll
        for (int j = 0; j < 4; ++j) {
            const int col = colBase + wn*64 + j*16 + (lane & 15);
            #pragma unroll
            for (int r = 0; r < 4; ++r)
                G[(size_t)(row + r) * H_DIM + col] = (f16)acc[i][j][r];
        }
    }
}

// ---------------- output GEMM: out = Hs @ Wout^T + bout (fp32 out) ----------------
__global__ __launch_bounds__(256) void k_out_gemm(
    const f16* __restrict__ Hs, const float* __restrict__ Wout,
    const float* __restrict__ bout, float* __restrict__ out)
{
    __shared__ f16 As[128 * 40];
    __shared__ f16 Bs[128 * 40];

    const int t = threadIdx.x;
    const int lane = t & 63;
    const int w  = t >> 6;
    const int wm = w & 1, wn = w >> 1;
    const int rowBase = blockIdx.x * 128;
    const int colBase = blockIdx.y * 128;

    const int srow = t >> 1;
    const int sk   = (t & 1) * 16;

    f32x4 acc[4][4] = {};

    for (int kt = 0; kt < H_DIM; kt += 32) {
        {
            const f16* ap = Hs + (size_t)(rowBase + srow) * H_DIM + kt + sk;
            *(f16x8*)&As[srow*40 + sk]     = *(const f16x8*)ap;
            *(f16x8*)&As[srow*40 + sk + 8] = *(const f16x8*)(ap + 8);
            const float* wp = Wout + (size_t)(colBase + srow) * H_DIM + kt + sk;
            f16x8 t0, t1;
            #pragma unroll
            for (int q = 0; q < 2; ++q) {
                float4 a = ((const float4*)wp)[q];
                t0[q*4+0] = (f16)a.x; t0[q*4+1] = (f16)a.y; t0[q*4+2] = (f16)a.z; t0[q*4+3] = (f16)a.w;
            }
            #pragma unroll
            for (int q = 0; q < 2; ++q) {
                float4 a = ((const float4*)wp)[q+2];
                t1[q*4+0] = (f16)a.x; t1[q*4+1] = (f16)a.y; t1[q*4+2] = (f16)a.z; t1[q*4+3] = (f16)a.w;
            }
            *(f16x8*)&Bs[srow*40 + sk]     = t0;
            *(f16x8*)&Bs[srow*40 + sk + 8] = t1;
        }
        __syncthreads();
        f16x8 af[4], bf[4];
        #pragma unroll
        for (int i = 0; i < 4; ++i)
            af[i] = *(const f16x8*)&As[(wm*64 + i*16 + (lane & 15))*40 + ((lane >> 4) * 8)];
        #pragma unroll
        for (int i = 0; i < 4; ++i)
            bf[i] = *(const f16x8*)&Bs[(wn*64 + i*16 + (lane & 15))*40 + ((lane >> 4) * 8)];
        #pragma unroll
        for (int i = 0; i < 4; ++i)
            #pragma unroll
            for (int j = 0; j < 4; ++j)
                acc[i][j] = __builtin_amdgcn_mfma_f32_16x16x32_f16(af[i], bf[j], acc[i][j], 0, 0, 0);
        __syncthreads();
    }
    #pragma unroll
    for (int i = 0; i < 4; ++i) {
        const int row = rowBase + wm*64 + i*16 + ((lane >> 4) * 4);
        #pragma unroll
        for (int j = 0; j < 4; ++j) {
            const int col = colBase + wn*64 + j*16 + (lane & 15);
            const float bb = bout[col];
            #pragma unroll
            for (int r = 0; r < 4; ++r)
                out[(size_t)(row + r) * O_DIM + col] = acc[i][j][r] + bb;
        }
    }
}

// ---------------- persistent recurrent kernel ----------------
// 64 WGs x 512 thr (8 waves). WG owns 16 hidden cols. Z and fp32 h-state live
// in registers. Handoff: Rh_all[step] / Hs[step] written sc0sc1 (MALL), read
// with plain cached loads (step-indexed => first-touch-after-write coherent).
// Sync: flag-array barrier via compiler agent atomics.
__global__ __launch_bounds__(512, 1) void k_recurrent(
    const f16* __restrict__ GR, const f16* __restrict__ GZ, const f16* __restrict__ GH,
    const float* __restrict__ WhR, const float* __restrict__ WhZ, const float* __restrict__ WhH,
    const float* __restrict__ bR, const float* __restrict__ bZ, const float* __restrict__ bH,
    f16* __restrict__ Rh_all, f16* __restrict__ Hs, unsigned* flg)
{
    __shared__ f16 WA[16 * 1032];   // WhR slice
    __shared__ f16 WB[16 * 1032];   // WhZ slice
    __shared__ f16 WC[16 * 1032];   // WhH slice

    const int t = threadIdx.x;
    const int lane = t & 63;
    const int w = t >> 6;
    const int wg = blockIdx.x;
    const int col0 = wg * 16;

    for (int i = t; i < 4096; i += 512) {
        int jj = i >> 8;
        int kk = (i & 255) << 2;
        float4 v = *(const float4*)(WhR + (size_t)(col0 + jj) * H_DIM + kk);
        f16x4 tv; tv[0] = (f16)v.x; tv[1] = (f16)v.y; tv[2] = (f16)v.z; tv[3] = (f16)v.w;
        *(f16x4*)&WA[jj * 1032 + kk] = tv;
        v = *(const float4*)(WhZ + (size_t)(col0 + jj) * H_DIM + kk);
        tv[0] = (f16)v.x; tv[1] = (f16)v.y; tv[2] = (f16)v.z; tv[3] = (f16)v.w;
        *(f16x4*)&WB[jj * 1032 + kk] = tv;
        v = *(const float4*)(WhH + (size_t)(col0 + jj) * H_DIM + kk);
        tv[0] = (f16)v.x; tv[1] = (f16)v.y; tv[2] = (f16)v.z; tv[3] = (f16)v.w;
        *(f16x4*)&WC[jj * 1032 + kk] = tv;
    }
    __syncthreads();

    const int brow = w * 16 + (lane & 15);   // batch row (B-col / D-col)
    const int arow = lane & 15;              // A-row into weight LDS
    const int kcol = (lane >> 4) * 8;        // k sub-offset (halves)
    const int ocl  = (lane >> 4) * 4;        // out-col offset (D-rows)

    const f32x4 bbr = *(const f32x4*)&bR[col0 + ocl];
    const f32x4 bbz = *(const f32x4*)&bZ[col0 + ocl];
    const f32x4 bbh = *(const f32x4*)&bH[col0 + ocl];

    const size_t eoff = (size_t)brow * H_DIM + col0 + ocl;
    const size_t koff = (size_t)brow * H_DIM + kcol;

#define CONS_RZ(B, VM)                                                           \
    asm volatile("s_waitcnt vmcnt(" #VM ")" ::: "memory");                       \
    __builtin_amdgcn_sched_barrier(0);                                           \
    _Pragma("unroll")                                                            \
    for (int i = 0; i < 8; ++i) {                                                \
        const int kk = (B) * 8 + i;                                              \
        f16x8 ar = *(const f16x8*)&WA[arow * 1032 + kk * 32 + kcol];             \
        f16x8 az = *(const f16x8*)&WB[arow * 1032 + kk * 32 + kcol];             \
        accR = __builtin_amdgcn_mfma_f32_16x16x32_f16(ar, fr[kk], accR, 0, 0, 0);\
        accZ = __builtin_amdgcn_mfma_f32_16x16x32_f16(az, fr[kk], accZ, 0, 0, 0);\
    }

#define CONS_H(B, VM)                                                            \
    asm volatile("s_waitcnt vmcnt(" #VM ")" ::: "memory");                       \
    __builtin_amdgcn_sched_barrier(0);                                           \
    _Pragma("unroll")                                                            \
    for (int i = 0; i < 8; ++i) {                                                \
        const int kk = (B) * 8 + i;                                              \
        f16x8 ah = *(const f16x8*)&WC[arow * 1032 + kk * 32 + kcol];             \
        accH = __builtin_amdgcn_mfma_f32_16x16x32_f16(ah, fr[kk], accH, 0, 0, 0);\
    }

    float h32r[4] = {0.f, 0.f, 0.f, 0.f};
    unsigned gen = 0;

    #pragma unroll 1
    for (int step = 0; step < T_STEPS; ++step) {
        const size_t sBH = (size_t)step * BH;
        // ---- phase 1: R and Z ----
        f32x4 accR = {}, accZ = {};
        f16x4 gr4 = *(const f16x4*)&GR[sBH + eoff];
        f16x4 gz4 = *(const f16x4*)&GZ[sBH + eoff];
        if (step > 0) {
            const f16* hb = Hs + (sBH - BH) + koff;
            f16x8 fr[32];
            Iss<0>::go(fr, hb);
            CONS_RZ(0, 24) CONS_RZ(1, 16) CONS_RZ(2, 8) CONS_RZ(3, 0)
        }
        float zr[4];
        f16x4 rhv;
        #pragma unroll
        for (int j = 0; j < 4; ++j) {
            float pr = accR[j] + (float)gr4[j] + bbr[j];
            float rr = 1.f / (1.f + __expf(-pr));
            rhv[j] = (f16)(rr * h32r[j]);
            float pz = accZ[j] + (float)gz4[j] + bbz[j];
            zr[j] = 1.f / (1.f + __expf(-pz));
        }
        gstore8_cc(Rh_all + sBH + eoff, rhv);
        fbar(flg, wg, ++gen, w, lane);

        // ---- phase 2: Hhat + h update ----
        f32x4 accH = {};
        f16x4 gh4 = *(const f16x4*)&GH[sBH + eoff];
        {
            const f16* rb = Rh_all + sBH + koff;
            f16x8 fr[32];
            Iss<0>::go(fr, rb);
            CONS_H(0, 24) CONS_H(1, 16) CONS_H(2, 8) CONS_H(3, 0)
        }
        f16x4 hv;
        #pragma unroll
        for (int j = 0; j < 4; ++j) {
            float ph = accH[j] + (float)gh4[j] + bbh[j];
            float e = __expf(2.f * ph);
            float th = 1.f - 2.f / (e + 1.f);
            float hn = zr[j] * h32r[j] + (1.f - zr[j]) * th;
            h32r[j] = hn;
            hv[j] = (f16)hn;
        }
        gstore8_cc(Hs + sBH + eoff, hv);
        if (step < T_STEPS - 1) fbar(flg, wg, ++gen, w, lane);
    }
#undef CONS_RZ
#undef CONS_H
}

extern "C" void kernel_launch(void* const* d_in, const int* in_sizes, int n_in,
                              void* d_out, int out_size, void* d_ws, size_t ws_size,
                              hipStream_t stream) {
    const float* x    = (const float*)d_in[0];
    const float* rn   = (const float*)d_in[1];
    const float* zn   = (const float*)d_in[2];
    const float* hn   = (const float*)d_in[3];
    const float* Wxz  = (const float*)d_in[4];
    const float* Wxr  = (const float*)d_in[5];
    const float* Wxh  = (const float*)d_in[6];
    const float* Whz  = (const float*)d_in[7];
    const float* bz   = (const float*)d_in[8];
    const float* Whr  = (const float*)d_in[9];
    const float* br   = (const float*)d_in[10];
    const float* Whh  = (const float*)d_in[11];
    const float* bh   = (const float*)d_in[12];
    const float* Wout = (const float*)d_in[13];
    const float* bout = (const float*)d_in[14];
    float* out = (float*)d_out;

    char* ws = (char*)d_ws;
    size_t off = 0;
    f16* GR     = (f16*)(ws + off); off += (size_t)TBROWS * H_DIM * 2;  // 64 MB
    f16* GZ     = (f16*)(ws + off); off += (size_t)TBROWS * H_DIM * 2;
    f16* GH     = (f16*)(ws + off); off += (size_t)TBROWS * H_DIM * 2;
    f16* Hs     = (f16*)(ws + off); off += (size_t)TBROWS * H_DIM * 2;
    f16* Rh_all = (f16*)(ws + off); off += (size_t)TBROWS * H_DIM * 2;
    unsigned* flg = (unsigned*)(ws + off); off += NWG * 16 * 4;

    k_init<<<1, 256, 0, stream>>>(flg);
    k_gate_gemm<<<dim3(TBROWS / 128, H_DIM / 128, 3), 256, 0, stream>>>(
        x, rn, zn, hn, Wxr, Wxz, Wxh, GR, GZ, GH);
    k_recurrent<<<NWG, 512, 0, stream>>>(
        GR, GZ, GH, Whr, Whz, Whh, br, bz, bh, Rh_all, Hs, flg);
    k_out_gemm<<<dim3(TBROWS / 128, O_DIM / 128), 256, 0, stream>>>(Hs, Wout, bout, out);
}

// Round 9
// 5757.650 us; speedup vs baseline: 2.7339x; 1.0420x over previous
//
#include <hip/hip_runtime.h>

typedef _Float16 f16;
typedef _Float16 f16x8 __attribute__((ext_vector_type(8)));
typedef _Float16 f16x4 __attribute__((ext_vector_type(4)));
typedef float    f32x4 __attribute__((ext_vector_type(4)));

#define T_STEPS 256
#define B_ROWS  128
#define I_DIM   1024
#define H_DIM   1024
#define O_DIM   512
#define TBROWS  (T_STEPS * B_ROWS)   // 32768
#define BH      (B_ROWS * H_DIM)     // 131072
#define NWG     64

// ---------------- init: zero flag array (REQUIRED each launch: 0xAA poison
// would compare >= gen and fake-pass the poll) ----------------
__global__ void k_init(unsigned* flg) {
    for (int i = threadIdx.x; i < 8 * NWG * 16; i += 256) flg[i] = 0u;
}

// ---------- cached load (L1+L2). Safe: every handoff address is
// first-touched AFTER its producer's MALL write (step-indexed buffers,
// dispatch-start acquire invalidated all L2s; prior-replay stale lines
// hold the same deterministic values). ----------
template<int K>
__device__ __forceinline__ f16x8 gload(const f16* p) {
    f16x8 r;
    asm volatile("global_load_dwordx4 %0, %1, off offset:%c2"
                 : "=v"(r) : "v"(p), "n"(K * 64));
    return r;
}
template<int K> struct Iss {
    static __device__ __forceinline__ void go(f16x8* fr, const f16* p) {
        fr[K] = gload<K>(p);
        Iss<K + 1>::go(fr, p);
    }
};
template<> struct Iss<32> {
    static __device__ __forceinline__ void go(f16x8*, const f16*) {}
};
// write-through to MALL (cross-XCD visible; no write-back false sharing)
__device__ __forceinline__ void gstore8_cc(f16* p, f16x4 v) {
    asm volatile("global_store_dwordx2 %0, %1, off sc0 sc1"
                 :: "v"(p), "v"(v) : "memory");
}

// ---------- per-row-group wave barrier ----------
// Row-group w (rows 16w..16w+16) couples only wave w of the 64 WGs.
// Publish: own-wave vmcnt(0) (stores at MALL), lane0 writes flag[w][wg].
// Poll: 64 lanes read the 64 group flags; divergent spin reconverges when
// all lanes see >= gen. No __syncthreads anywhere in the loop.
__device__ __forceinline__ void wpub(unsigned* flg, int grp, int wg, unsigned gen, int lane) {
    asm volatile("s_waitcnt vmcnt(0) lgkmcnt(0)" ::: "memory");
    if (lane == 0)
        __hip_atomic_store(&flg[(grp * NWG + wg) * 16], gen, __ATOMIC_RELAXED, __HIP_MEMORY_SCOPE_AGENT);
    __builtin_amdgcn_sched_barrier(0);
}
__device__ __forceinline__ void wpoll(const unsigned* flg, int grp, unsigned gen, int lane) {
    while (__hip_atomic_load(&flg[(grp * NWG + lane) * 16], __ATOMIC_RELAXED, __HIP_MEMORY_SCOPE_AGENT) < gen)
        __builtin_amdgcn_s_sleep(1);
    __builtin_amdgcn_sched_barrier(0);
}

// ---------------- gate GEMM: G_g = (x + noise_g) @ Wx_g^T  (fp16 out) ----------------
__global__ __launch_bounds__(256) void k_gate_gemm(
    const float* __restrict__ x,
    const float* __restrict__ nR, const float* __restrict__ nZ, const float* __restrict__ nH,
    const float* __restrict__ WxR, const float* __restrict__ WxZ, const float* __restrict__ WxH,
    f16* __restrict__ GR, f16* __restrict__ GZ, f16* __restrict__ GH)
{
    const int g = blockIdx.z;
    const float* noise = (g == 0) ? nR : (g == 1) ? nZ : nH;
    const float* W     = (g == 0) ? WxR : (g == 1) ? WxZ : WxH;
    f16* G             = (g == 0) ? GR : (g == 1) ? GZ : GH;

    __shared__ f16 As[128 * 40];
    __shared__ f16 Bs[128 * 40];

    const int t = threadIdx.x;
    const int lane = t & 63;
    const int w  = t >> 6;
    const int wm = w & 1, wn = w >> 1;
    const int rowBase = blockIdx.x * 128;
    const int colBase = blockIdx.y * 128;

    const int srow = t >> 1;
    const int sk   = (t & 1) * 16;

    f32x4 acc[4][4] = {};

    for (int kt = 0; kt < I_DIM; kt += 32) {
        {
            const float* xp = x     + (size_t)(rowBase + srow) * I_DIM + kt + sk;
            const float* np = noise + (size_t)(rowBase + srow) * I_DIM + kt + sk;
            f16x8 t0, t1;
            #pragma unroll
            for (int q = 0; q < 2; ++q) {
                float4 a = ((const float4*)xp)[q];
                float4 b = ((const float4*)np)[q];
                t0[q*4+0] = (f16)(a.x + b.x); t0[q*4+1] = (f16)(a.y + b.y);
                t0[q*4+2] = (f16)(a.z + b.z); t0[q*4+3] = (f16)(a.w + b.w);
            }
            #pragma unroll
            for (int q = 0; q < 2; ++q) {
                float4 a = ((const float4*)xp)[q+2];
                float4 b = ((const float4*)np)[q+2];
                t1[q*4+0] = (f16)(a.x + b.x); t1[q*4+1] = (f16)(a.y + b.y);
                t1[q*4+2] = (f16)(a.z + b.z); t1[q*4+3] = (f16)(a.w + b.w);
            }
            *(f16x8*)&As[srow*40 + sk]     = t0;
            *(f16x8*)&As[srow*40 + sk + 8] = t1;
            const float* wp = W + (size_t)(colBase + srow) * I_DIM + kt + sk;
            #pragma unroll
            for (int q = 0; q < 2; ++q) {
                float4 a = ((const float4*)wp)[q];
                t0[q*4+0] = (f16)a.x; t0[q*4+1] = (f16)a.y; t0[q*4+2] = (f16)a.z; t0[q*4+3] = (f16)a.w;
            }
            #pragma unroll
            for (int q = 0; q < 2; ++q) {
                float4 a = ((const float4*)wp)[q+2];
                t1[q*4+0] = (f16)a.x; t1[q*4+1] = (f16)a.y; t1[q*4+2] = (f16)a.z; t1[q*4+3] = (f16)a.w;
            }
            *(f16x8*)&Bs[srow*40 + sk]     = t0;
            *(f16x8*)&Bs[srow*40 + sk + 8] = t1;
        }
        __syncthreads();
        f16x8 af[4], bf[4];
        #pragma unroll
        for (int i = 0; i < 4; ++i)
            af[i] = *(const f16x8*)&As[(wm*64 + i*16 + (lane & 15))*40 + ((lane >> 4) * 8)];
        #pragma unroll
        for (int i = 0; i < 4; ++i)
            bf[i] = *(const f16x8*)&Bs[(wn*64 + i*16 + (lane & 15))*40 + ((lane >> 4) * 8)];
        #pragma unroll
        for (int i = 0; i < 4; ++i)
            #pragma unroll
            for (int j = 0; j < 4; ++j)
                acc[i][j] = __builtin_amdgcn_mfma_f32_16x16x32_f16(af[i], bf[j], acc[i][j], 0, 0, 0);
        __syncthreads();
    }
    #pragma unroll
    for (int i = 0; i < 4; ++i) {
        const int row = rowBase + wm*64 + i*16 + ((lane >> 4) * 4);
        #pragma unroll
        for (int j = 0; j < 4; ++j) {
            const int col = colBase + wn*64 + j*16 + (lane & 15);
            #pragma unroll
            for (int r = 0; r < 4; ++r)
                G[(size_t)(row + r) * H_DIM + col] = (f16)acc[i][j][r];
        }
    }
}

// ---------------- output GEMM: out = Hs @ Wout^T + bout (fp32 out) ----------------
__global__ __launch_bounds__(256) void k_out_gemm(
    const f16* __restrict__ Hs, const float* __restrict__ Wout,
    const float* __restrict__ bout, float* __restrict__ out)
{
    __shared__ f16 As[128 * 40];
    __shared__ f16 Bs[128 * 40];

    const int t = threadIdx.x;
    const int lane = t & 63;
    const int w  = t >> 6;
    const int wm = w & 1, wn = w >> 1;
    const int rowBase = blockIdx.x * 128;
    const int colBase = blockIdx.y * 128;

    const int srow = t >> 1;
    const int sk   = (t & 1) * 16;

    f32x4 acc[4][4] = {};

    for (int kt = 0; kt < H_DIM; kt += 32) {
        {
            const f16* ap = Hs + (size_t)(rowBase + srow) * H_DIM + kt + sk;
            *(f16x8*)&As[srow*40 + sk]     = *(const f16x8*)ap;
            *(f16x8*)&As[srow*40 + sk + 8] = *(const f16x8*)(ap + 8);
            const float* wp = Wout + (size_t)(colBase + srow) * H_DIM + kt + sk;
            f16x8 t0, t1;
            #pragma unroll
            for (int q = 0; q < 2; ++q) {
                float4 a = ((const float4*)wp)[q];
                t0[q*4+0] = (f16)a.x; t0[q*4+1] = (f16)a.y; t0[q*4+2] = (f16)a.z; t0[q*4+3] = (f16)a.w;
            }
            #pragma unroll
            for (int q = 0; q < 2; ++q) {
                float4 a = ((const float4*)wp)[q+2];
                t1[q*4+0] = (f16)a.x; t1[q*4+1] = (f16)a.y; t1[q*4+2] = (f16)a.z; t1[q*4+3] = (f16)a.w;
            }
            *(f16x8*)&Bs[srow*40 + sk]     = t0;
            *(f16x8*)&Bs[srow*40 + sk + 8] = t1;
        }
        __syncthreads();
        f16x8 af[4], bf[4];
        #pragma unroll
        for (int i = 0; i < 4; ++i)
            af[i] = *(const f16x8*)&As[(wm*64 + i*16 + (lane & 15))*40 + ((lane >> 4) * 8)];
        #pragma unroll
        for (int i = 0; i < 4; ++i)
            bf[i] = *(const f16x8*)&Bs[(wn*64 + i*16 + (lane & 15))*40 + ((lane >> 4) * 8)];
        #pragma unroll
        for (int i = 0; i < 4; ++i)
            #pragma unroll
            for (int j = 0; j < 4; ++j)
                acc[i][j] = __builtin_amdgcn_mfma_f32_16x16x32_f16(af[i], bf[j], acc[i][j], 0, 0, 0);
        __syncthreads();
    }
    #pragma unroll
    for (int i = 0; i < 4; ++i) {
        const int row = rowBase + wm*64 + i*16 + ((lane >> 4) * 4);
        #pragma unroll
        for (int j = 0; j < 4; ++j) {
            const int col = colBase + wn*64 + j*16 + (lane & 15);
            const float bb = bout[col];
            #pragma unroll
            for (int r = 0; r < 4; ++r)
                out[(size_t)(row + r) * O_DIM + col] = acc[i][j][r] + bb;
        }
    }
}

// ---------------- persistent recurrent kernel ----------------
// 64 WGs x 512 thr (8 waves). Wave w of WG g: batch rows 16w..+16, hidden
// cols 16g..+16. 8 independent row-group chains, each synced by its own
// 64-wave flag group. Z and fp32 h-state live in registers. Handoff:
// Rh_all[step] / Hs[step] written sc0sc1 (MALL), read with plain cached
// loads (step-indexed => first-touch-after-write coherent). Gate loads
// issued before the poll so their latency hides under the wait.
__global__ __launch_bounds__(512, 1) void k_recurrent(
    const f16* __restrict__ GR, const f16* __restrict__ GZ, const f16* __restrict__ GH,
    const float* __restrict__ WhR, const float* __restrict__ WhZ, const float* __restrict__ WhH,
    const float* __restrict__ bR, const float* __restrict__ bZ, const float* __restrict__ bH,
    f16* __restrict__ Rh_all, f16* __restrict__ Hs, unsigned* flg)
{
    __shared__ f16 WA[16 * 1032];   // WhR slice
    __shared__ f16 WB[16 * 1032];   // WhZ slice
    __shared__ f16 WC[16 * 1032];   // WhH slice

    const int t = threadIdx.x;
    const int lane = t & 63;
    const int w = t >> 6;
    const int wg = blockIdx.x;
    const int col0 = wg * 16;

    for (int i = t; i < 4096; i += 512) {
        int jj = i >> 8;
        int kk = (i & 255) << 2;
        float4 v = *(const float4*)(WhR + (size_t)(col0 + jj) * H_DIM + kk);
        f16x4 tv; tv[0] = (f16)v.x; tv[1] = (f16)v.y; tv[2] = (f16)v.z; tv[3] = (f16)v.w;
        *(f16x4*)&WA[jj * 1032 + kk] = tv;
        v = *(const float4*)(WhZ + (size_t)(col0 + jj) * H_DIM + kk);
        tv[0] = (f16)v.x; tv[1] = (f16)v.y; tv[2] = (f16)v.z; tv[3] = (f16)v.w;
        *(f16x4*)&WB[jj * 1032 + kk] = tv;
        v = *(const float4*)(WhH + (size_t)(col0 + jj) * H_DIM + kk);
        tv[0] = (f16)v.x; tv[1] = (f16)v.y; tv[2] = (f16)v.z; tv[3] = (f16)v.w;
        *(f16x4*)&WC[jj * 1032 + kk] = tv;
    }
    __syncthreads();   // one-time: weights staged; waves never sync again

    const int brow = w * 16 + (lane & 15);   // batch row (B-col / D-col)
    const int arow = lane & 15;              // A-row into weight LDS
    const int kcol = (lane >> 4) * 8;        // k sub-offset (halves)
    const int ocl  = (lane >> 4) * 4;        // out-col offset (D-rows)

    const f32x4 bbr = *(const f32x4*)&bR[col0 + ocl];
    const f32x4 bbz = *(const f32x4*)&bZ[col0 + ocl];
    const f32x4 bbh = *(const f32x4*)&bH[col0 + ocl];

    const size_t eoff = (size_t)brow * H_DIM + col0 + ocl;
    const size_t koff = (size_t)brow * H_DIM + kcol;

#define CONS_RZ(B, VM)                                                           \
    asm volatile("s_waitcnt vmcnt(" #VM ")" ::: "memory");                       \
    __builtin_amdgcn_sched_barrier(0);                                           \
    _Pragma("unroll")                                                            \
    for (int i = 0; i < 8; ++i) {                                                \
        const int kk = (B) * 8 + i;                                              \
        f16x8 ar = *(const f16x8*)&WA[arow * 1032 + kk * 32 + kcol];             \
        f16x8 az = *(const f16x8*)&WB[arow * 1032 + kk * 32 + kcol];             \
        accR = __builtin_amdgcn_mfma_f32_16x16x32_f16(ar, fr[kk], accR, 0, 0, 0);\
        accZ = __builtin_amdgcn_mfma_f32_16x16x32_f16(az, fr[kk], accZ, 0, 0, 0);\
    }

#define CONS_H(B, VM)                                                            \
    asm volatile("s_waitcnt vmcnt(" #VM ")" ::: "memory");                       \
    __builtin_amdgcn_sched_barrier(0);                                           \
    _Pragma("unroll")                                                            \
    for (int i = 0; i < 8; ++i) {                                                \
        const int kk = (B) * 8 + i;                                              \
        f16x8 ah = *(const f16x8*)&WC[arow * 1032 + kk * 32 + kcol];             \
        accH = __builtin_amdgcn_mfma_f32_16x16x32_f16(ah, fr[kk], accH, 0, 0, 0);\
    }

    float h32r[4] = {0.f, 0.f, 0.f, 0.f};

    #pragma unroll 1
    for (int step = 0; step < T_STEPS; ++step) {
        const size_t sBH = (size_t)step * BH;
        // ---- phase 1: R and Z ----
        f32x4 accR = {}, accZ = {};
        // gate loads issued BEFORE the poll: latency hides under the wait
        f16x4 gr4 = *(const f16x4*)&GR[sBH + eoff];
        f16x4 gz4 = *(const f16x4*)&GZ[sBH + eoff];
        if (step > 0) {
            wpoll(flg, w, 2u * (unsigned)step, lane);   // wait h(step-1) group w
            const f16* hb = Hs + (sBH - BH) + koff;
            f16x8 fr[32];
            Iss<0>::go(fr, hb);
            CONS_RZ(0, 24) CONS_RZ(1, 16) CONS_RZ(2, 8) CONS_RZ(3, 0)
        }
        float zr[4];
        f16x4 rhv;
        #pragma unroll
        for (int j = 0; j < 4; ++j) {
            float pr = accR[j] + (float)gr4[j] + bbr[j];
            float rr = 1.f / (1.f + __expf(-pr));
            rhv[j] = (f16)(rr * h32r[j]);
            float pz = accZ[j] + (float)gz4[j] + bbz[j];
            zr[j] = 1.f / (1.f + __expf(-pz));
        }
        gstore8_cc(Rh_all + sBH + eoff, rhv);
        wpub(flg, w, wg, 2u * (unsigned)step + 1u, lane);

        // ---- phase 2: Hhat + h update ----
        f32x4 accH = {};
        f16x4 gh4 = *(const f16x4*)&GH[sBH + eoff];     // prefetch under poll
        wpoll(flg, w, 2u * (unsigned)step + 1u, lane);  // wait Rh(step) group w
        {
            const f16* rb = Rh_all + sBH + koff;
            f16x8 fr[32];
            Iss<0>::go(fr, rb);
            CONS_H(0, 24) CONS_H(1, 16) CONS_H(2, 8) CONS_H(3, 0)
        }
        f16x4 hv;
        #pragma unroll
        for (int j = 0; j < 4; ++j) {
            float ph = accH[j] + (float)gh4[j] + bbh[j];
            float e = __expf(2.f * ph);
            float th = 1.f - 2.f / (e + 1.f);
            float hn = zr[j] * h32r[j] + (1.f - zr[j]) * th;
            h32r[j] = hn;
            hv[j] = (f16)hn;
        }
        gstore8_cc(Hs + sBH + eoff, hv);
        if (step < T_STEPS - 1) wpub(flg, w, wg, 2u * (unsigned)step + 2u, lane);
    }
    asm volatile("s_waitcnt vmcnt(0)" ::: "memory");
#undef CONS_RZ
#undef CONS_H
}

extern "C" void kernel_launch(void* const* d_in, const int* in_sizes, int n_in,
                              void* d_out, int out_size, void* d_ws, size_t ws_size,
                              hipStream_t stream) {
    const float* x    = (const float*)d_in[0];
    const float* rn   = (const float*)d_in[1];
    const float* zn   = (const float*)d_in[2];
    const float* hn   = (const float*)d_in[3];
    const float* Wxz  = (const float*)d_in[4];
    const float* Wxr  = (const float*)d_in[5];
    const float* Wxh  = (const float*)d_in[6];
    const float* Whz  = (const float*)d_in[7];
    const float* bz   = (const float*)d_in[8];
    const float* Whr  = (const float*)d_in[9];
    const float* br   = (const float*)d_in[10];
    const float* Whh  = (const float*)d_in[11];
    const float* bh   = (const float*)d_in[12];
    const float* Wout = (const float*)d_in[13];
    const float* bout = (const float*)d_in[14];
    float* out = (float*)d_out;

    char* ws = (char*)d_ws;
    size_t off = 0;
    f16* GR     = (f16*)(ws + off); off += (size_t)TBROWS * H_DIM * 2;  // 64 MB
    f16* GZ     = (f16*)(ws + off); off += (size_t)TBROWS * H_DIM * 2;
    f16* GH     = (f16*)(ws + off); off += (size_t)TBROWS * H_DIM * 2;
    f16* Hs     = (f16*)(ws + off); off += (size_t)TBROWS * H_DIM * 2;
    f16* Rh_all = (f16*)(ws + off); off += (size_t)TBROWS * H_DIM * 2;
    unsigned* flg = (unsigned*)(ws + off); off += 8 * NWG * 16 * 4;

    k_init<<<1, 256, 0, stream>>>(flg);
    k_gate_gemm<<<dim3(TBROWS / 128, H_DIM / 128, 3), 256, 0, stream>>>(
        x, rn, zn, hn, Wxr, Wxz, Wxh, GR, GZ, GH);
    k_recurrent<<<NWG, 512, 0, stream>>>(
        GR, GZ, GH, Whr, Whz, Whh, br, bz, bh, Rh_all, Hs, flg);
    k_out_gemm<<<dim3(TBROWS / 128, O_DIM / 128), 256, 0, stream>>>(Hs, Wout, bout, out);
}

// Round 10
// 5592.356 us; speedup vs baseline: 2.8147x; 1.0296x over previous
//
#include <hip/hip_runtime.h>

typedef _Float16 f16;
typedef _Float16 f16x8 __attribute__((ext_vector_type(8)));
typedef _Float16 f16x4 __attribute__((ext_vector_type(4)));
typedef float    f32x4 __attribute__((ext_vector_type(4)));

#define T_STEPS 256
#define B_ROWS  128
#define I_DIM   1024
#define H_DIM   1024
#define O_DIM   512
#define TBROWS  (T_STEPS * B_ROWS)   // 32768
#define BH      (B_ROWS * H_DIM)     // 131072
#define NWG     64

// ---------------- init: zero flag + agg arrays (REQUIRED each launch:
// 0xAA poison would compare >= gen and fake-pass the polls) ----------------
__global__ void k_init(unsigned* flg) {
    for (int i = threadIdx.x; i < (8 * NWG + 8) * 16; i += 256) flg[i] = 0u;
}

// ---------- cached load (L1+L2). Safe: every handoff address is
// first-touched AFTER its producer's MALL write (step-indexed buffers,
// dispatch-start acquire invalidated all L2s; prior-replay stale lines
// hold the same deterministic values). ----------
template<int K>
__device__ __forceinline__ f16x8 gload(const f16* p) {
    f16x8 r;
    asm volatile("global_load_dwordx4 %0, %1, off offset:%c2"
                 : "=v"(r) : "v"(p), "n"(K * 64));
    return r;
}
template<int K> struct Iss {
    static __device__ __forceinline__ void go(f16x8* fr, const f16* p) {
        fr[K] = gload<K>(p);
        Iss<K + 1>::go(fr, p);
    }
};
template<> struct Iss<32> {
    static __device__ __forceinline__ void go(f16x8*, const f16*) {}
};
// write-through to MALL (cross-XCD visible; no write-back false sharing)
__device__ __forceinline__ void gstore8_cc(f16* p, f16x4 v) {
    asm volatile("global_store_dwordx2 %0, %1, off sc0 sc1"
                 :: "v"(p), "v"(v) : "memory");
}

// ---------- hierarchical per-row-group wave barrier ----------
// Publish (unchanged from R9): own-wave vmcnt(0), lane0 writes flag[w][wg]
// (64B-padded line, no store contention).
// Wait (new): aggregator wave (wg == grp) scans the 64 producer flags and
// publishes one combined flag agg[grp]; the other 63 waves of the group
// poll ONLY agg[grp] (single line, ~1 request/iter). Cuts poll traffic
// ~30x — R9's 512 waves x 64-line scans were ~2-4 TB/s of MALL flood,
// jamming the acks/fills the chain waits on.
__device__ __forceinline__ void wpub(unsigned* flg, int grp, int wg, unsigned gen, int lane) {
    asm volatile("s_waitcnt vmcnt(0) lgkmcnt(0)" ::: "memory");
    if (lane == 0)
        __hip_atomic_store(&flg[(grp * NWG + wg) * 16], gen, __ATOMIC_RELAXED, __HIP_MEMORY_SCOPE_AGENT);
    __builtin_amdgcn_sched_barrier(0);
}
__device__ __forceinline__ void wpoll(unsigned* flg, unsigned* agg, int grp, int wg, unsigned gen, int lane) {
    if (wg == grp) {
        // aggregator: divergent per-lane spin over the 64 producer flags
        while (__hip_atomic_load(&flg[(grp * NWG + lane) * 16], __ATOMIC_RELAXED, __HIP_MEMORY_SCOPE_AGENT) < gen)
            __builtin_amdgcn_s_sleep(1);
        if (lane < 2)
            __hip_atomic_store(&agg[grp * 16 + lane], gen, __ATOMIC_RELAXED, __HIP_MEMORY_SCOPE_AGENT);
    } else {
        // consumers: poll the combined flag only (lane&1 keeps the address
        // lane-variant so the atomic load stays a VMEM op)
        while (__hip_atomic_load(&agg[grp * 16 + (lane & 1)], __ATOMIC_RELAXED, __HIP_MEMORY_SCOPE_AGENT) < gen)
            __builtin_amdgcn_s_sleep(1);
    }
    __builtin_amdgcn_sched_barrier(0);
}

// ---------------- gate GEMM: G_g = (x + noise_g) @ Wx_g^T  (fp16 out) ----------------
__global__ __launch_bounds__(256) void k_gate_gemm(
    const float* __restrict__ x,
    const float* __restrict__ nR, const float* __restrict__ nZ, const float* __restrict__ nH,
    const float* __restrict__ WxR, const float* __restrict__ WxZ, const float* __restrict__ WxH,
    f16* __restrict__ GR, f16* __restrict__ GZ, f16* __restrict__ GH)
{
    const int g = blockIdx.z;
    const float* noise = (g == 0) ? nR : (g == 1) ? nZ : nH;
    const float* W     = (g == 0) ? WxR : (g == 1) ? WxZ : WxH;
    f16* G             = (g == 0) ? GR : (g == 1) ? GZ : GH;

    __shared__ f16 As[128 * 40];
    __shared__ f16 Bs[128 * 40];

    const int t = threadIdx.x;
    const int lane = t & 63;
    const int w  = t >> 6;
    const int wm = w & 1, wn = w >> 1;
    const int rowBase = blockIdx.x * 128;
    const int colBase = blockIdx.y * 128;

    const int srow = t >> 1;
    const int sk   = (t & 1) * 16;

    f32x4 acc[4][4] = {};

    for (int kt = 0; kt < I_DIM; kt += 32) {
        {
            const float* xp = x     + (size_t)(rowBase + srow) * I_DIM + kt + sk;
            const float* np = noise + (size_t)(rowBase + srow) * I_DIM + kt + sk;
            f16x8 t0, t1;
            #pragma unroll
            for (int q = 0; q < 2; ++q) {
                float4 a = ((const float4*)xp)[q];
                float4 b = ((const float4*)np)[q];
                t0[q*4+0] = (f16)(a.x + b.x); t0[q*4+1] = (f16)(a.y + b.y);
                t0[q*4+2] = (f16)(a.z + b.z); t0[q*4+3] = (f16)(a.w + b.w);
            }
            #pragma unroll
            for (int q = 0; q < 2; ++q) {
                float4 a = ((const float4*)xp)[q+2];
                float4 b = ((const float4*)np)[q+2];
                t1[q*4+0] = (f16)(a.x + b.x); t1[q*4+1] = (f16)(a.y + b.y);
                t1[q*4+2] = (f16)(a.z + b.z); t1[q*4+3] = (f16)(a.w + b.w);
            }
            *(f16x8*)&As[srow*40 + sk]     = t0;
            *(f16x8*)&As[srow*40 + sk + 8] = t1;
            const float* wp = W + (size_t)(colBase + srow) * I_DIM + kt + sk;
            #pragma unroll
            for (int q = 0; q < 2; ++q) {
                float4 a = ((const float4*)wp)[q];
                t0[q*4+0] = (f16)a.x; t0[q*4+1] = (f16)a.y; t0[q*4+2] = (f16)a.z; t0[q*4+3] = (f16)a.w;
            }
            #pragma unroll
            for (int q = 0; q < 2; ++q) {
                float4 a = ((const float4*)wp)[q+2];
                t1[q*4+0] = (f16)a.x; t1[q*4+1] = (f16)a.y; t1[q*4+2] = (f16)a.z; t1[q*4+3] = (f16)a.w;
            }
            *(f16x8*)&Bs[srow*40 + sk]     = t0;
            *(f16x8*)&Bs[srow*40 + sk + 8] = t1;
        }
        __syncthreads();
        f16x8 af[4], bf[4];
        #pragma unroll
        for (int i = 0; i < 4; ++i)
            af[i] = *(const f16x8*)&As[(wm*64 + i*16 + (lane & 15))*40 + ((lane >> 4) * 8)];
        #pragma unroll
        for (int i = 0; i < 4; ++i)
            bf[i] = *(const f16x8*)&Bs[(wn*64 + i*16 + (lane & 15))*40 + ((lane >> 4) * 8)];
        #pragma unroll
        for (int i = 0; i < 4; ++i)
            #pragma unroll
            for (int j = 0; j < 4; ++j)
                acc[i][j] = __builtin_amdgcn_mfma_f32_16x16x32_f16(af[i], bf[j], acc[i][j], 0, 0, 0);
        __syncthreads();
    }
    #pragma unroll
    for (int i = 0; i < 4; ++i) {
        const int row = rowBase + wm*64 + i*16 + ((lane >> 4) * 4);
        #pragma unroll
        for (int j = 0; j < 4; ++j) {
            const int col = colBase + wn*64 + j*16 + (lane & 15);
            #pragma unroll
            for (int r = 0; r < 4; ++r)
                G[(size_t)(row + r) * H_DIM + col] = (f16)acc[i][j][r];
        }
    }
}

// ---------------- output GEMM: out = Hs @ Wout^T + bout (fp32 out) ----------------
__global__ __launch_bounds__(256) void k_out_gemm(
    const f16* __restrict__ Hs, const float* __restrict__ Wout,
    const float* __restrict__ bout, float* __restrict__ out)
{
    __shared__ f16 As[128 * 40];
    __shared__ f16 Bs[128 * 40];

    const int t = threadIdx.x;
    const int lane = t & 63;
    const int w  = t >> 6;
    const int wm = w & 1, wn = w >> 1;
    const int rowBase = blockIdx.x * 128;
    const int colBase = blockIdx.y * 128;

    const int srow = t >> 1;
    const int sk   = (t & 1) * 16;

    f32x4 acc[4][4] = {};

    for (int kt = 0; kt < H_DIM; kt += 32) {
        {
            const f16* ap = Hs + (size_t)(rowBase + srow) * H_DIM + kt + sk;
            *(f16x8*)&As[srow*40 + sk]     = *(const f16x8*)ap;
            *(f16x8*)&As[srow*40 + sk + 8] = *(const f16x8*)(ap + 8);
            const float* wp = Wout + (size_t)(colBase + srow) * H_DIM + kt + sk;
            f16x8 t0, t1;
            #pragma unroll
            for (int q = 0; q < 2; ++q) {
                float4 a = ((const float4*)wp)[q];
                t0[q*4+0] = (f16)a.x; t0[q*4+1] = (f16)a.y; t0[q*4+2] = (f16)a.z; t0[q*4+3] = (f16)a.w;
            }
            #pragma unroll
            for (int q = 0; q < 2; ++q) {
                float4 a = ((const float4*)wp)[q+2];
                t1[q*4+0] = (f16)a.x; t1[q*4+1] = (f16)a.y; t1[q*4+2] = (f16)a.z; t1[q*4+3] = (f16)a.w;
            }
            *(f16x8*)&Bs[srow*40 + sk]     = t0;
            *(f16x8*)&Bs[srow*40 + sk + 8] = t1;
        }
        __syncthreads();
        f16x8 af[4], bf[4];
        #pragma unroll
        for (int i = 0; i < 4; ++i)
            af[i] = *(const f16x8*)&As[(wm*64 + i*16 + (lane & 15))*40 + ((lane >> 4) * 8)];
        #pragma unroll
        for (int i = 0; i < 4; ++i)
            bf[i] = *(const f16x8*)&Bs[(wn*64 + i*16 + (lane & 15))*40 + ((lane >> 4) * 8)];
        #pragma unroll
        for (int i = 0; i < 4; ++i)
            #pragma unroll
            for (int j = 0; j < 4; ++j)
                acc[i][j] = __builtin_amdgcn_mfma_f32_16x16x32_f16(af[i], bf[j], acc[i][j], 0, 0, 0);
        __syncthreads();
    }
    #pragma unroll
    for (int i = 0; i < 4; ++i) {
        const int row = rowBase + wm*64 + i*16 + ((lane >> 4) * 4);
        #pragma unroll
        for (int j = 0; j < 4; ++j) {
            const int col = colBase + wn*64 + j*16 + (lane & 15);
            const float bb = bout[col];
            #pragma unroll
            for (int r = 0; r < 4; ++r)
                out[(size_t)(row + r) * O_DIM + col] = acc[i][j][r] + bb;
        }
    }
}

// ---------------- persistent recurrent kernel ----------------
// 64 WGs x 512 thr (8 waves). Wave w of WG g: batch rows 16w..+16, hidden
// cols 16g..+16. 8 independent row-group chains, each synced by its own
// hierarchical flag group (aggregator wave = wave w of WG w). Z and fp32
// h-state live in registers. Handoff: Rh_all[step] / Hs[step] written
// sc0sc1 (MALL), read with plain cached loads (step-indexed =>
// first-touch-after-write coherent). Gate loads issued before the poll
// so their latency hides under the wait.
__global__ __launch_bounds__(512, 1) void k_recurrent(
    const f16* __restrict__ GR, const f16* __restrict__ GZ, const f16* __restrict__ GH,
    const float* __restrict__ WhR, const float* __restrict__ WhZ, const float* __restrict__ WhH,
    const float* __restrict__ bR, const float* __restrict__ bZ, const float* __restrict__ bH,
    f16* __restrict__ Rh_all, f16* __restrict__ Hs, unsigned* flg)
{
    __shared__ f16 WA[16 * 1032];   // WhR slice
    __shared__ f16 WB[16 * 1032];   // WhZ slice
    __shared__ f16 WC[16 * 1032];   // WhH slice

    unsigned* agg = flg + 8 * NWG * 16;

    const int t = threadIdx.x;
    const int lane = t & 63;
    const int w = t >> 6;
    const int wg = blockIdx.x;
    const int col0 = wg * 16;

    for (int i = t; i < 4096; i += 512) {
        int jj = i >> 8;
        int kk = (i & 255) << 2;
        float4 v = *(const float4*)(WhR + (size_t)(col0 + jj) * H_DIM + kk);
        f16x4 tv; tv[0] = (f16)v.x; tv[1] = (f16)v.y; tv[2] = (f16)v.z; tv[3] = (f16)v.w;
        *(f16x4*)&WA[jj * 1032 + kk] = tv;
        v = *(const float4*)(WhZ + (size_t)(col0 + jj) * H_DIM + kk);
        tv[0] = (f16)v.x; tv[1] = (f16)v.y; tv[2] = (f16)v.z; tv[3] = (f16)v.w;
        *(f16x4*)&WB[jj * 1032 + kk] = tv;
        v = *(const float4*)(WhH + (size_t)(col0 + jj) * H_DIM + kk);
        tv[0] = (f16)v.x; tv[1] = (f16)v.y; tv[2] = (f16)v.z; tv[3] = (f16)v.w;
        *(f16x4*)&WC[jj * 1032 + kk] = tv;
    }
    __syncthreads();   // one-time: weights staged; waves never sync again

    const int brow = w * 16 + (lane & 15);   // batch row (B-col / D-col)
    const int arow = lane & 15;              // A-row into weight LDS
    const int kcol = (lane >> 4) * 8;        // k sub-offset (halves)
    const int ocl  = (lane >> 4) * 4;        // out-col offset (D-rows)

    const f32x4 bbr = *(const f32x4*)&bR[col0 + ocl];
    const f32x4 bbz = *(const f32x4*)&bZ[col0 + ocl];
    const f32x4 bbh = *(const f32x4*)&bH[col0 + ocl];

    const size_t eoff = (size_t)brow * H_DIM + col0 + ocl;
    const size_t koff = (size_t)brow * H_DIM + kcol;

#define CONS_RZ(B, VM)                                                           \
    asm volatile("s_waitcnt vmcnt(" #VM ")" ::: "memory");                       \
    __builtin_amdgcn_sched_barrier(0);                                           \
    _Pragma("unroll")                                                            \
    for (int i = 0; i < 8; ++i) {                                                \
        const int kk = (B) * 8 + i;                                              \
        f16x8 ar = *(const f16x8*)&WA[arow * 1032 + kk * 32 + kcol];             \
        f16x8 az = *(const f16x8*)&WB[arow * 1032 + kk * 32 + kcol];             \
        accR = __builtin_amdgcn_mfma_f32_16x16x32_f16(ar, fr[kk], accR, 0, 0, 0);\
        accZ = __builtin_amdgcn_mfma_f32_16x16x32_f16(az, fr[kk], accZ, 0, 0, 0);\
    }

#define CONS_H(B, VM)                                                            \
    asm volatile("s_waitcnt vmcnt(" #VM ")" ::: "memory");                       \
    __builtin_amdgcn_sched_barrier(0);                                           \
    _Pragma("unroll")                                                            \
    for (int i = 0; i < 8; ++i) {                                                \
        const int kk = (B) * 8 + i;                                              \
        f16x8 ah = *(const f16x8*)&WC[arow * 1032 + kk * 32 + kcol];             \
        accH = __builtin_amdgcn_mfma_f32_16x16x32_f16(ah, fr[kk], accH, 0, 0, 0);\
    }

    float h32r[4] = {0.f, 0.f, 0.f, 0.f};

    #pragma unroll 1
    for (int step = 0; step < T_STEPS; ++step) {
        const size_t sBH = (size_t)step * BH;
        // ---- phase 1: R and Z ----
        f32x4 accR = {}, accZ = {};
        // gate loads issued BEFORE the poll: latency hides under the wait
        f16x4 gr4 = *(const f16x4*)&GR[sBH + eoff];
        f16x4 gz4 = *(const f16x4*)&GZ[sBH + eoff];
        if (step > 0) {
            wpoll(flg, agg, w, wg, 2u * (unsigned)step, lane);   // wait h(step-1)
            const f16* hb = Hs + (sBH - BH) + koff;
            f16x8 fr[32];
            Iss<0>::go(fr, hb);
            CONS_RZ(0, 24) CONS_RZ(1, 16) CONS_RZ(2, 8) CONS_RZ(3, 0)
        }
        float zr[4];
        f16x4 rhv;
        #pragma unroll
        for (int j = 0; j < 4; ++j) {
            float pr = accR[j] + (float)gr4[j] + bbr[j];
            float rr = 1.f / (1.f + __expf(-pr));
            rhv[j] = (f16)(rr * h32r[j]);
            float pz = accZ[j] + (float)gz4[j] + bbz[j];
            zr[j] = 1.f / (1.f + __expf(-pz));
        }
        gstore8_cc(Rh_all + sBH + eoff, rhv);
        wpub(flg, w, wg, 2u * (unsigned)step + 1u, lane);

        // ---- phase 2: Hhat + h update ----
        f32x4 accH = {};
        f16x4 gh4 = *(const f16x4*)&GH[sBH + eoff];              // prefetch under poll
        wpoll(flg, agg, w, wg, 2u * (unsigned)step + 1u, lane);  // wait Rh(step)
        {
            const f16* rb = Rh_all + sBH + koff;
            f16x8 fr[32];
            Iss<0>::go(fr, rb);
            CONS_H(0, 24) CONS_H(1, 16) CONS_H(2, 8) CONS_H(3, 0)
        }
        f16x4 hv;
        #pragma unroll
        for (int j = 0; j < 4; ++j) {
            float ph = accH[j] + (float)gh4[j] + bbh[j];
            float e = __expf(2.f * ph);
            float th = 1.f - 2.f / (e + 1.f);
            float hn = zr[j] * h32r[j] + (1.f - zr[j]) * th;
            h32r[j] = hn;
            hv[j] = (f16)hn;
        }
        gstore8_cc(Hs + sBH + eoff, hv);
        if (step < T_STEPS - 1) wpub(flg, w, wg, 2u * (unsigned)step + 2u, lane);
    }
    asm volatile("s_waitcnt vmcnt(0)" ::: "memory");
#undef CONS_RZ
#undef CONS_H
}

extern "C" void kernel_launch(void* const* d_in, const int* in_sizes, int n_in,
                              void* d_out, int out_size, void* d_ws, size_t ws_size,
                              hipStream_t stream) {
    const float* x    = (const float*)d_in[0];
    const float* rn   = (const float*)d_in[1];
    const float* zn   = (const float*)d_in[2];
    const float* hn   = (const float*)d_in[3];
    const float* Wxz  = (const float*)d_in[4];
    const float* Wxr  = (const float*)d_in[5];
    const float* Wxh  = (const float*)d_in[6];
    const float* Whz  = (const float*)d_in[7];
    const float* bz   = (const float*)d_in[8];
    const float* Whr  = (const float*)d_in[9];
    const float* br   = (const float*)d_in[10];
    const float* Whh  = (const float*)d_in[11];
    const float* bh   = (const float*)d_in[12];
    const float* Wout = (const float*)d_in[13];
    const float* bout = (const float*)d_in[14];
    float* out = (float*)d_out;

    char* ws = (char*)d_ws;
    size_t off = 0;
    f16* GR     = (f16*)(ws + off); off += (size_t)TBROWS * H_DIM * 2;  // 64 MB
    f16* GZ     = (f16*)(ws + off); off += (size_t)TBROWS * H_DIM * 2;
    f16* GH     = (f16*)(ws + off); off += (size_t)TBROWS * H_DIM * 2;
    f16* Hs     = (f16*)(ws + off); off += (size_t)TBROWS * H_DIM * 2;
    f16* Rh_all = (f16*)(ws + off); off += (size_t)TBROWS * H_DIM * 2;
    unsigned* flg = (unsigned*)(ws + off); off += (8 * NWG + 8) * 16 * 4;

    k_init<<<1, 256, 0, stream>>>(flg);
    k_gate_gemm<<<dim3(TBROWS / 128, H_DIM / 128, 3), 256, 0, stream>>>(
        x, rn, zn, hn, Wxr, Wxz, Wxh, GR, GZ, GH);
    k_recurrent<<<NWG, 512, 0, stream>>>(
        GR, GZ, GH, Whr, Whz, Whh, br, bz, bh, Rh_all, Hs, flg);
    k_out_gemm<<<dim3(TBROWS / 128, O_DIM / 128), 256, 0, stream>>>(Hs, Wout, bout, out);
}